// Round 3
// baseline (2278.796 us; speedup 1.0000x reference)
//
#include <hip/hip_runtime.h>

// LinearREncoder: concat(x,y) -> relu(W1)->relu(W2)->(aggregate)->W3 -> masked mean
// B=64 N=512 XD=YD=128 DIN=256 HD=4096 RD=1024, M=B*N=32768 tokens.
// bf16 MFMA (16x16x32) 128x128x64 tiles; layer-3 after masked-sum (linearity);
// prefix-mask M-tile skip; H1 chunked 4x.
// R3: LDS tiles stored in MFMA *fragment order* (chunk = ((mi*2+s)*64+lane)) so
// every ds_read_b128 is 64 lanes x 16B contiguous -> zero bank conflicts under
// any phasing model. R2's XOR swizzle measured 25 conflict-cyc per b128 (1.3e8
// total) -> LDS-bound at ~390 TF; this restores the m97 compute-bound regime.

using u16 = unsigned short;
typedef float f32x4 __attribute__((ext_vector_type(4)));
typedef short s16x8 __attribute__((ext_vector_type(8)));

__device__ __forceinline__ u16 f2bf(float f) {
  union { float f; unsigned u; } v; v.f = f;
  unsigned r = (v.u + 0x7fffu + ((v.u >> 16) & 1u)) >> 16;  // RNE
  return (u16)r;
}

// ---------------- prep kernels ----------------

// lens[b] = sum of mask ints (harness passes bool as int32, values 0/1)
__global__ void count_k(const int* __restrict__ mask, int* __restrict__ lens) {
  int b = blockIdx.x, l = threadIdx.x;  // 64 blocks x 64 threads
  const int4* row = (const int4*)(mask + (size_t)b * 512);
  int4 v0 = row[l];
  int4 v1 = row[l + 64];
  int s = v0.x + v0.y + v0.z + v0.w + v1.x + v1.y + v1.z + v1.w;
  #pragma unroll
  for (int o = 32; o; o >>= 1) s += __shfl_down(s, o);
  if (l == 0) lens[b] = s;
}

// A[m][0:128]=bf16(x[m]), A[m][128:256]=bf16(y[m])
__global__ void build_a(const float* __restrict__ x, const float* __restrict__ y,
                        u16* __restrict__ A) {
  int i4 = blockIdx.x * 256 + threadIdx.x;  // one float4 each; grid 8192
  int e = i4 * 4;
  int m = e >> 8, c = e & 255;
  const float* src = (c < 128) ? (x + (size_t)m * 128 + c)
                               : (y + (size_t)m * 128 + (c - 128));
  float4 v = *(const float4*)src;
  ushort4 o;
  o.x = f2bf(v.x); o.y = f2bf(v.y); o.z = f2bf(v.z); o.w = f2bf(v.w);
  *(ushort4*)&A[e] = o;
}

// out[C][R] bf16 = transpose of in[R][C] f32
__global__ void transpose_k(const float* __restrict__ in, u16* __restrict__ out,
                            int R, int C) {
  __shared__ float tile[32][33];
  int c0 = blockIdx.x * 32, r0 = blockIdx.y * 32;
  int tx = threadIdx.x;
  #pragma unroll
  for (int yy = threadIdx.y; yy < 32; yy += 8)
    tile[yy][tx] = in[(size_t)(r0 + yy) * C + c0 + tx];
  __syncthreads();
  #pragma unroll
  for (int yy = threadIdx.y; yy < 32; yy += 8)
    out[(size_t)(c0 + yy) * R + r0 + tx] = f2bf(tile[tx][yy]);
}

// Sn[m][k] = bf16(S[m][k] / len[m]) for m<64, else 0  (S rows 64..127 are zeroed)
__global__ void sn_k(const float* __restrict__ S, const int* __restrict__ lens,
                     u16* __restrict__ Sn) {
  int i4 = blockIdx.x * 256 + threadIdx.x;  // grid 512
  int e = i4 * 4;
  int m = e >> 12;
  float inv = (m < 64) ? (1.0f / (float)lens[m]) : 0.0f;
  float4 v = *(const float4*)(S + e);
  ushort4 o;
  o.x = f2bf(v.x * inv); o.y = f2bf(v.y * inv);
  o.z = f2bf(v.z * inv); o.w = f2bf(v.w * inv);
  *(ushort4*)&Sn[e] = o;
}

// ---------------- main GEMM ----------------
// C[128x128] tile = A[128xK] @ BT[NxK]^T.  BK=64, 4 waves in 2x2, 64x64/wave.
// LDS tile layout (fragment order): chunk index ci = ((mi*2+s)*64 + quad*16 + l15)
// holds global (row = mi*16+l15, kchunk = s*4+quad); each chunk = 16B (8 bf16).
// Fragment read for (wave-row mi, k-step s) = chunk base + lane  -> contiguous.
// MODE 0: Hout[m][n] = bf16(relu(acc + bias[n]))                  (layer 1)
// MODE 1: Sout[b][n] += sum over valid rows of relu(acc+bias[n])  (layer 2 + pool)
// MODE 2: Fout[m][n] = acc + bias[n], rows < 64 only              (layer 3)
template <int MODE>
__global__ __launch_bounds__(256) void gemm_k(
    const u16* __restrict__ A, int lda, const u16* __restrict__ BT, int ldb,
    const float* __restrict__ bias, u16* __restrict__ Hout,
    float* __restrict__ Sout, float* __restrict__ Fout,
    const int* __restrict__ lens, int K, int Nld, int m_row_base) {
  __shared__ union {
    struct { u16 a[128 * 64]; u16 b[128 * 64]; } st;  // 16KB + 16KB
    u16 outT[128 * 136];                              // MODE0 repack (pad 8)
    float colsum[128];                                // MODE1 reduce
  } sm;

  const int mt = blockIdx.y;
  const int n0 = blockIdx.x * 128;
  int lenb = 1 << 30;
  int bidx = 0;
  if constexpr (MODE < 2) {
    const int gm0 = m_row_base + mt * 128;
    bidx = gm0 >> 9;              // batch id (512 tokens/batch)
    const int m0b = gm0 & 511;    // tile start within batch
    const int len = lens[bidx];
    if (m0b >= len) return;       // whole tile masked out -> skip
    lenb = len - m0b;             // rows < lenb are valid
  }

  const int tid = threadIdx.x;
  const int wave = tid >> 6;
  const int lane = tid & 63;
  const int wm = wave >> 1, wn = wave & 1;
  const int quad = lane >> 4, l15 = lane & 15;

  f32x4 acc[4][4];
  #pragma unroll
  for (int i = 0; i < 4; i++)
    #pragma unroll
    for (int j = 0; j < 4; j++) acc[i][j] = (f32x4){0.f, 0.f, 0.f, 0.f};

  // Staging pointers: instruction (wave,il) fills chunk group t = wave*4+il
  // (t: mi = t>>1, s = t&1); lane supplies (quad = lane>>4, l15 = lane&15).
  // Global addr = row (mi*16+l15), kchunk (s*4+quad). Each instruction covers
  // 16 full 64B lines (4 lanes merge per line) -> 100% line utilization.
  const u16* ag[4]; const u16* bg[4];
  #pragma unroll
  for (int il = 0; il < 4; ++il) {
    int t = wave * 4 + il;
    int m = (t >> 1) * 16 + l15;
    int c = (t & 1) * 4 + quad;
    ag[il] = A + (size_t)(mt * 128 + m) * lda + c * 8;
    bg[il] = BT + (size_t)(n0 + m) * ldb + c * 8;
  }

  for (int kt = 0; kt < K; kt += 64) {
    #pragma unroll
    for (int il = 0; il < 4; ++il)
      __builtin_amdgcn_global_load_lds(
          (const __attribute__((address_space(1))) void*)(ag[il] + kt),
          (__attribute__((address_space(3))) void*)(&sm.st.a[(wave * 4 + il) * 512]),
          16, 0, 0);
    #pragma unroll
    for (int il = 0; il < 4; ++il)
      __builtin_amdgcn_global_load_lds(
          (const __attribute__((address_space(1))) void*)(bg[il] + kt),
          (__attribute__((address_space(3))) void*)(&sm.st.b[(wave * 4 + il) * 512]),
          16, 0, 0);
    __syncthreads();
    #pragma unroll
    for (int s = 0; s < 2; ++s) {  // two k=32 steps
      s16x8 af[4], bf[4];
      #pragma unroll
      for (int i = 0; i < 4; i++)
        af[i] = *(const s16x8*)&sm.st.a[(((wm * 4 + i) * 2 + s) * 64 + lane) * 8];
      #pragma unroll
      for (int j = 0; j < 4; j++)
        bf[j] = *(const s16x8*)&sm.st.b[(((wn * 4 + j) * 2 + s) * 64 + lane) * 8];
      #pragma unroll
      for (int i = 0; i < 4; i++)
        #pragma unroll
        for (int j = 0; j < 4; j++)
          acc[i][j] = __builtin_amdgcn_mfma_f32_16x16x32_bf16(af[i], bf[j],
                                                              acc[i][j], 0, 0, 0);
    }
    __syncthreads();
  }

  // epilogues (C/D layout: col = lane&15, row = quad*4 + reg)
  if constexpr (MODE == 0) {
    float bb[4];
    #pragma unroll
    for (int j = 0; j < 4; j++) bb[j] = bias[n0 + wn * 64 + j * 16 + l15];
    #pragma unroll
    for (int i = 0; i < 4; i++)
      #pragma unroll
      for (int j = 0; j < 4; j++) {
        int col = wn * 64 + j * 16 + l15;
        #pragma unroll
        for (int r = 0; r < 4; r++) {
          int row = wm * 64 + i * 16 + quad * 4 + r;
          float v = acc[i][j][r] + bb[j];
          v = v > 0.f ? v : 0.f;
          sm.outT[row * 136 + col] = f2bf(v);
        }
      }
    __syncthreads();
    #pragma unroll
    for (int u = 0; u < 16; ++u) {
      int e = u * 256 + tid;
      int row = e >> 5, c4 = (e & 31) * 4;
      *(uint2*)&Hout[(size_t)(mt * 128 + row) * Nld + n0 + c4] =
          *(const uint2*)&sm.outT[row * 136 + c4];
    }
  } else if constexpr (MODE == 1) {
    if (tid < 128) sm.colsum[tid] = 0.f;
    __syncthreads();
    float bb[4];
    #pragma unroll
    for (int j = 0; j < 4; j++) bb[j] = bias[n0 + wn * 64 + j * 16 + l15];
    #pragma unroll
    for (int j = 0; j < 4; j++) {
      float v = 0.f;
      #pragma unroll
      for (int i = 0; i < 4; i++)
        #pragma unroll
        for (int r = 0; r < 4; r++) {
          int row = wm * 64 + i * 16 + quad * 4 + r;
          float t = acc[i][j][r] + bb[j];
          t = t > 0.f ? t : 0.f;
          v += (row < lenb) ? t : 0.f;
        }
      v += __shfl_xor(v, 16);
      v += __shfl_xor(v, 32);
      if (lane < 16) atomicAdd(&sm.colsum[wn * 64 + j * 16 + lane], v);
    }
    __syncthreads();
    if (tid < 128) atomicAdd(&Sout[(size_t)bidx * 4096 + n0 + tid], sm.colsum[tid]);
  } else {
    float bb[4];
    #pragma unroll
    for (int j = 0; j < 4; j++) bb[j] = bias[n0 + wn * 64 + j * 16 + l15];
    #pragma unroll
    for (int i = 0; i < 4; i++)
      #pragma unroll
      for (int j = 0; j < 4; j++) {
        int col = wn * 64 + j * 16 + l15;
        #pragma unroll
        for (int r = 0; r < 4; r++) {
          int row = wm * 64 + i * 16 + quad * 4 + r;
          if (row < 64) Fout[(size_t)row * Nld + n0 + col] = acc[i][j][r] + bb[j];
        }
      }
  }
}

// ---------------- host ----------------
extern "C" void kernel_launch(void* const* d_in, const int* in_sizes, int n_in,
                              void* d_out, int out_size, void* d_ws, size_t ws_size,
                              hipStream_t stream) {
  const float* x  = (const float*)d_in[0];
  const float* y  = (const float*)d_in[1];
  const int* mask = (const int*)d_in[2];
  const float* W1 = (const float*)d_in[3];
  const float* b1 = (const float*)d_in[4];
  const float* W2 = (const float*)d_in[5];
  const float* b2 = (const float*)d_in[6];
  const float* W3 = (const float*)d_in[7];
  const float* b3 = (const float*)d_in[8];
  float* out = (float*)d_out;

  char* ws = (char*)d_ws;
  size_t off = 0;
  auto alloc = [&](size_t bytes) {
    char* p = ws + off;
    off += (bytes + 255) & ~(size_t)255;
    return p;
  };
  int* lens = (int*)alloc(64 * 4);
  float* S  = (float*)alloc((size_t)128 * 4096 * 4);   // padded to 128 rows
  u16* Sn   = (u16*)alloc((size_t)128 * 4096 * 2);
  u16* W1T  = (u16*)alloc((size_t)4096 * 256 * 2);
  u16* W2T  = (u16*)alloc((size_t)4096 * 4096 * 2);
  u16* W3T  = (u16*)alloc((size_t)1024 * 4096 * 2);
  u16* Abuf = (u16*)alloc((size_t)32768 * 256 * 2);
  u16* H1   = (u16*)alloc((size_t)8192 * 4096 * 2);    // one M-chunk
  if (off > ws_size) return;  // workspace too small -> loud failure

  hipMemsetAsync(S, 0, (size_t)128 * 4096 * 4, stream);
  count_k<<<64, 64, 0, stream>>>(mask, lens);
  build_a<<<8192, 256, 0, stream>>>(x, y, Abuf);
  transpose_k<<<dim3(4096 / 32, 256 / 32), dim3(32, 8), 0, stream>>>(W1, W1T, 256, 4096);
  transpose_k<<<dim3(4096 / 32, 4096 / 32), dim3(32, 8), 0, stream>>>(W2, W2T, 4096, 4096);
  transpose_k<<<dim3(1024 / 32, 4096 / 32), dim3(32, 8), 0, stream>>>(W3, W3T, 4096, 1024);

  for (int c = 0; c < 4; ++c) {  // 8192-token chunks
    gemm_k<0><<<dim3(32, 64), 256, 0, stream>>>(
        Abuf + (size_t)c * 8192 * 256, 256, W1T, 256, b1, H1, nullptr, nullptr,
        lens, 256, 4096, c * 8192);
    gemm_k<1><<<dim3(32, 64), 256, 0, stream>>>(
        H1, 4096, W2T, 4096, b2, nullptr, S, nullptr,
        lens, 4096, 4096, c * 8192);
  }
  sn_k<<<512, 256, 0, stream>>>(S, lens, Sn);
  gemm_k<2><<<dim3(8, 1), 256, 0, stream>>>(
      Sn, 4096, W3T, 4096, b3, nullptr, nullptr, out, nullptr, 4096, 1024, 0);
}

// Round 4
// 1897.929 us; speedup vs baseline: 1.2007x; 1.2007x over previous
//
#include <hip/hip_runtime.h>

// LinearREncoder: concat(x,y) -> relu(W1)->relu(W2)->(aggregate)->W3 -> masked mean
// B=64 N=512 XD=YD=128 DIN=256 HD=4096 RD=1024, M=B*N=32768 tokens.
// bf16 MFMA (16x16x32) 128x128x64 tiles; layer-3 after masked-sum (linearity);
// prefix-mask M-tile skip; H1 chunked 4x.
// R4: XCD-locality swizzle (each virtual XCD owns a 4-n-tile B strip -> B stays
// L2-hot, A kt-slices fetched once per XCD). R2/R3 showed identical LDS-conflict
// counts for two optimal-by-construction read layouts -> stall is sub-L2 memory
// (62% barrier-drain, MfmaUtil 16.6%). Staging restored to R2's 128B-row pattern.
// LDS union trimmed to exactly 32KB; gemm<2> tail split-K x8.

using u16 = unsigned short;
typedef float f32x4 __attribute__((ext_vector_type(4)));
typedef short s16x8 __attribute__((ext_vector_type(8)));

__device__ __forceinline__ u16 f2bf(float f) {
  union { float f; unsigned u; } v; v.f = f;
  unsigned r = (v.u + 0x7fffu + ((v.u >> 16) & 1u)) >> 16;  // RNE
  return (u16)r;
}

// ---------------- prep kernels ----------------

// lens[b] = sum of mask ints (harness passes bool as int32, values 0/1)
__global__ void count_k(const int* __restrict__ mask, int* __restrict__ lens) {
  int b = blockIdx.x, l = threadIdx.x;  // 64 blocks x 64 threads
  const int4* row = (const int4*)(mask + (size_t)b * 512);
  int4 v0 = row[l];
  int4 v1 = row[l + 64];
  int s = v0.x + v0.y + v0.z + v0.w + v1.x + v1.y + v1.z + v1.w;
  #pragma unroll
  for (int o = 32; o; o >>= 1) s += __shfl_down(s, o);
  if (l == 0) lens[b] = s;
}

// A[m][0:128]=bf16(x[m]), A[m][128:256]=bf16(y[m])
__global__ void build_a(const float* __restrict__ x, const float* __restrict__ y,
                        u16* __restrict__ A) {
  int i4 = blockIdx.x * 256 + threadIdx.x;  // one float4 each; grid 8192
  int e = i4 * 4;
  int m = e >> 8, c = e & 255;
  const float* src = (c < 128) ? (x + (size_t)m * 128 + c)
                               : (y + (size_t)m * 128 + (c - 128));
  float4 v = *(const float4*)src;
  ushort4 o;
  o.x = f2bf(v.x); o.y = f2bf(v.y); o.z = f2bf(v.z); o.w = f2bf(v.w);
  *(ushort4*)&A[e] = o;
}

// out[C][R] bf16 = transpose of in[R][C] f32
__global__ void transpose_k(const float* __restrict__ in, u16* __restrict__ out,
                            int R, int C) {
  __shared__ float tile[32][33];
  int c0 = blockIdx.x * 32, r0 = blockIdx.y * 32;
  int tx = threadIdx.x;
  #pragma unroll
  for (int yy = threadIdx.y; yy < 32; yy += 8)
    tile[yy][tx] = in[(size_t)(r0 + yy) * C + c0 + tx];
  __syncthreads();
  #pragma unroll
  for (int yy = threadIdx.y; yy < 32; yy += 8)
    out[(size_t)(c0 + yy) * R + r0 + tx] = f2bf(tile[tx][yy]);
}

// Sn[m][k] = bf16(S[m][k] / len[m]) for m<64, else 0  (S rows 64..127 are zeroed)
__global__ void sn_k(const float* __restrict__ S, const int* __restrict__ lens,
                     u16* __restrict__ Sn) {
  int i4 = blockIdx.x * 256 + threadIdx.x;  // grid 512
  int e = i4 * 4;
  int m = e >> 12;
  float inv = (m < 64) ? (1.0f / (float)lens[m]) : 0.0f;
  float4 v = *(const float4*)(S + e);
  ushort4 o;
  o.x = f2bf(v.x * inv); o.y = f2bf(v.y * inv);
  o.z = f2bf(v.z * inv); o.w = f2bf(v.w * inv);
  *(ushort4*)&Sn[e] = o;
}

// ---------------- main GEMM ----------------
// C[128x128] tile = A[128xK] @ BT[NxK]^T.  BK=64, 4 waves in 2x2, 64x64/wave.
// Block swizzle (MODE<2): linear = by*32+bx; vxcd = linear&7; slot = linear>>3;
//   mt = slot>>2; nt = vxcd*4 + (slot&3).
// Each vxcd owns n-tiles [4v,4v+4): B strip (4MB for W2T) stays hot in its L2;
// consecutive slots share mt so the A kt-slice is fetched ~once per XCD.
// MODE 0: Hout[m][n] = bf16(relu(acc + bias[n]))                  (layer 1)
// MODE 1: Sout[b][n] += sum over valid rows of relu(acc+bias[n])  (layer 2 + pool)
// MODE 2: Fout[m][n] += acc (+bias on k-slice 0), rows<64; split-K over blockIdx.y
template <int MODE>
__global__ __launch_bounds__(256) void gemm_k(
    const u16* __restrict__ A, int lda, const u16* __restrict__ BT, int ldb,
    const float* __restrict__ bias, u16* __restrict__ Hout,
    float* __restrict__ Sout, float* __restrict__ Fout,
    const int* __restrict__ lens, int K, int Nld, int m_row_base) {
  __shared__ union {
    struct { u16 a[128 * 64]; u16 b[128 * 64]; } st;  // 16KB + 16KB
    u16 outT[128 * 128];                              // MODE0 repack (32KB)
    float colsum[128];                                // MODE1 reduce
  } sm;

  int mt, n0, k0, kend;
  if constexpr (MODE < 2) {
    int linear = blockIdx.y * 32 + blockIdx.x;
    int vxcd = linear & 7, slot = linear >> 3;
    mt = slot >> 2;
    n0 = (vxcd * 4 + (slot & 3)) * 128;
    k0 = 0; kend = K;
  } else {
    mt = 0;
    n0 = blockIdx.x * 128;
    k0 = blockIdx.y * 512;      // split-K x8
    kend = k0 + 512;
  }

  int lenb = 1 << 30;
  int bidx = 0;
  if constexpr (MODE < 2) {
    const int gm0 = m_row_base + mt * 128;
    bidx = gm0 >> 9;              // batch id (512 tokens/batch)
    const int m0b = gm0 & 511;    // tile start within batch
    const int len = lens[bidx];
    if (m0b >= len) return;       // whole tile masked out -> skip
    lenb = len - m0b;             // rows < lenb are valid
  }

  const int tid = threadIdx.x;
  const int wave = tid >> 6;
  const int lane = tid & 63;
  const int wm = wave >> 1, wn = wave & 1;
  const int quad = lane >> 4, l15 = lane & 15;

  f32x4 acc[4][4];
  #pragma unroll
  for (int i = 0; i < 4; i++)
    #pragma unroll
    for (int j = 0; j < 4; j++) acc[i][j] = (f32x4){0.f, 0.f, 0.f, 0.f};

  // Staging (R2 pattern): chunk ci = (wave*4+il)*64+lane; row = ci>>3,
  // kchunk = (ci&7)^(row&7) -> 8 lanes x 16B = 128B contiguous per row.
  const u16* ag[4]; const u16* bg[4];
  #pragma unroll
  for (int il = 0; il < 4; ++il) {
    int ci = (wave * 4 + il) * 64 + lane;
    int m = ci >> 3, c = (ci & 7) ^ (m & 7);
    ag[il] = A + (size_t)(mt * 128 + m) * lda + c * 8;
    bg[il] = BT + (size_t)(n0 + m) * ldb + c * 8;
  }

  for (int kt = k0; kt < kend; kt += 64) {
    #pragma unroll
    for (int il = 0; il < 4; ++il)
      __builtin_amdgcn_global_load_lds(
          (const __attribute__((address_space(1))) void*)(ag[il] + kt),
          (__attribute__((address_space(3))) void*)(&sm.st.a[(wave * 4 + il) * 512]),
          16, 0, 0);
    #pragma unroll
    for (int il = 0; il < 4; ++il)
      __builtin_amdgcn_global_load_lds(
          (const __attribute__((address_space(1))) void*)(bg[il] + kt),
          (__attribute__((address_space(3))) void*)(&sm.st.b[(wave * 4 + il) * 512]),
          16, 0, 0);
    __syncthreads();
    #pragma unroll
    for (int s = 0; s < 2; ++s) {  // two k=32 steps
      s16x8 af[4], bf[4];
      #pragma unroll
      for (int i = 0; i < 4; i++) {
        int m = wm * 64 + i * 16 + l15;
        int c = s * 4 + quad;
        af[i] = *(const s16x8*)&sm.st.a[(m * 8 + (c ^ (m & 7))) * 8];
      }
      #pragma unroll
      for (int j = 0; j < 4; j++) {
        int n = wn * 64 + j * 16 + l15;
        int c = s * 4 + quad;
        bf[j] = *(const s16x8*)&sm.st.b[(n * 8 + (c ^ (n & 7))) * 8];
      }
      #pragma unroll
      for (int i = 0; i < 4; i++)
        #pragma unroll
        for (int j = 0; j < 4; j++)
          acc[i][j] = __builtin_amdgcn_mfma_f32_16x16x32_bf16(af[i], bf[j],
                                                              acc[i][j], 0, 0, 0);
    }
    __syncthreads();
  }

  // epilogues (C/D layout: col = lane&15, row = quad*4 + reg)
  if constexpr (MODE == 0) {
    float bb[4];
    #pragma unroll
    for (int j = 0; j < 4; j++) bb[j] = bias[n0 + wn * 64 + j * 16 + l15];
    #pragma unroll
    for (int i = 0; i < 4; i++)
      #pragma unroll
      for (int j = 0; j < 4; j++) {
        int col = wn * 64 + j * 16 + l15;
        #pragma unroll
        for (int r = 0; r < 4; r++) {
          int row = wm * 64 + i * 16 + quad * 4 + r;
          float v = acc[i][j][r] + bb[j];
          v = v > 0.f ? v : 0.f;
          sm.outT[row * 128 + col] = f2bf(v);
        }
      }
    __syncthreads();
    #pragma unroll
    for (int u = 0; u < 16; ++u) {
      int e = u * 256 + tid;
      int row = e >> 5, c4 = (e & 31) * 4;
      *(uint2*)&Hout[(size_t)(mt * 128 + row) * Nld + n0 + c4] =
          *(const uint2*)&sm.outT[row * 128 + c4];
    }
  } else if constexpr (MODE == 1) {
    if (tid < 128) sm.colsum[tid] = 0.f;
    __syncthreads();
    float bb[4];
    #pragma unroll
    for (int j = 0; j < 4; j++) bb[j] = bias[n0 + wn * 64 + j * 16 + l15];
    #pragma unroll
    for (int j = 0; j < 4; j++) {
      float v = 0.f;
      #pragma unroll
      for (int i = 0; i < 4; i++)
        #pragma unroll
        for (int r = 0; r < 4; r++) {
          int row = wm * 64 + i * 16 + quad * 4 + r;
          float t = acc[i][j][r] + bb[j];
          t = t > 0.f ? t : 0.f;
          v += (row < lenb) ? t : 0.f;
        }
      v += __shfl_xor(v, 16);
      v += __shfl_xor(v, 32);
      if (lane < 16) atomicAdd(&sm.colsum[wn * 64 + j * 16 + lane], v);
    }
    __syncthreads();
    if (tid < 128) atomicAdd(&Sout[(size_t)bidx * 4096 + n0 + tid], sm.colsum[tid]);
  } else {
    float bb[4];
    #pragma unroll
    for (int j = 0; j < 4; j++)
      bb[j] = (blockIdx.y == 0) ? bias[n0 + wn * 64 + j * 16 + l15] : 0.f;
    #pragma unroll
    for (int i = 0; i < 4; i++)
      #pragma unroll
      for (int j = 0; j < 4; j++) {
        int col = wn * 64 + j * 16 + l15;
        #pragma unroll
        for (int r = 0; r < 4; r++) {
          int row = wm * 64 + i * 16 + quad * 4 + r;
          if (row < 64)
            atomicAdd(&Fout[(size_t)row * Nld + n0 + col], acc[i][j][r] + bb[j]);
        }
      }
  }
}

// ---------------- host ----------------
extern "C" void kernel_launch(void* const* d_in, const int* in_sizes, int n_in,
                              void* d_out, int out_size, void* d_ws, size_t ws_size,
                              hipStream_t stream) {
  const float* x  = (const float*)d_in[0];
  const float* y  = (const float*)d_in[1];
  const int* mask = (const int*)d_in[2];
  const float* W1 = (const float*)d_in[3];
  const float* b1 = (const float*)d_in[4];
  const float* W2 = (const float*)d_in[5];
  const float* b2 = (const float*)d_in[6];
  const float* W3 = (const float*)d_in[7];
  const float* b3 = (const float*)d_in[8];
  float* out = (float*)d_out;

  char* ws = (char*)d_ws;
  size_t off = 0;
  auto alloc = [&](size_t bytes) {
    char* p = ws + off;
    off += (bytes + 255) & ~(size_t)255;
    return p;
  };
  int* lens = (int*)alloc(64 * 4);
  float* S  = (float*)alloc((size_t)128 * 4096 * 4);   // padded to 128 rows
  u16* Sn   = (u16*)alloc((size_t)128 * 4096 * 2);
  u16* W1T  = (u16*)alloc((size_t)4096 * 256 * 2);
  u16* W2T  = (u16*)alloc((size_t)4096 * 4096 * 2);
  u16* W3T  = (u16*)alloc((size_t)1024 * 4096 * 2);
  u16* Abuf = (u16*)alloc((size_t)32768 * 256 * 2);
  u16* H1   = (u16*)alloc((size_t)8192 * 4096 * 2);    // one M-chunk
  if (off > ws_size) return;  // workspace too small -> loud failure

  hipMemsetAsync(S, 0, (size_t)128 * 4096 * 4, stream);
  hipMemsetAsync(out, 0, (size_t)64 * 1024 * 4, stream);  // split-K accumulator
  count_k<<<64, 64, 0, stream>>>(mask, lens);
  build_a<<<8192, 256, 0, stream>>>(x, y, Abuf);
  transpose_k<<<dim3(4096 / 32, 256 / 32), dim3(32, 8), 0, stream>>>(W1, W1T, 256, 4096);
  transpose_k<<<dim3(4096 / 32, 4096 / 32), dim3(32, 8), 0, stream>>>(W2, W2T, 4096, 4096);
  transpose_k<<<dim3(1024 / 32, 4096 / 32), dim3(32, 8), 0, stream>>>(W3, W3T, 4096, 1024);

  for (int c = 0; c < 4; ++c) {  // 8192-token chunks
    gemm_k<0><<<dim3(32, 64), 256, 0, stream>>>(
        Abuf + (size_t)c * 8192 * 256, 256, W1T, 256, b1, H1, nullptr, nullptr,
        lens, 256, 4096, c * 8192);
    gemm_k<1><<<dim3(32, 64), 256, 0, stream>>>(
        H1, 4096, W2T, 4096, b2, nullptr, S, nullptr,
        lens, 4096, 4096, c * 8192);
  }
  sn_k<<<512, 256, 0, stream>>>(S, lens, Sn);
  gemm_k<2><<<dim3(8, 8), 256, 0, stream>>>(
      Sn, 4096, W3T, 4096, b3, nullptr, nullptr, out, nullptr, 4096, 1024, 0);
}

// Round 6
// 1617.182 us; speedup vs baseline: 1.4091x; 1.1736x over previous
//
#include <hip/hip_runtime.h>

// LinearREncoder: concat(x,y) -> relu(W1)->relu(W2)->(aggregate)->W3 -> masked mean
// B=64 N=512 XD=YD=128 DIN=256 HD=4096 RD=1024, M=B*N=32768 tokens.
// bf16 MFMA (16x16x32) 128x128x64 tiles; layer-3 after masked-sum (linearity).
// R5: persistent 1024-block work-queue GEMMs (compacted valid-tile list),
// ws-adaptive H1 chunking. R6 fix: MODE 2 nslots was 1 -> only block x=0 ran,
// cols 128.. stayed zero (absmax 0.2578 = max|ref|). Now nslots = gridDim.x.

using u16 = unsigned short;
typedef float f32x4 __attribute__((ext_vector_type(4)));
typedef short s16x8 __attribute__((ext_vector_type(8)));

__device__ __forceinline__ u16 f2bf(float f) {
  union { float f; unsigned u; } v; v.f = f;
  unsigned r = (v.u + 0x7fffu + ((v.u >> 16) & 1u)) >> 16;  // RNE
  return (u16)r;
}

// ---------------- prep kernels ----------------

// lens[b] = sum of mask ints (harness passes bool as int32, values 0/1)
__global__ void count_k(const int* __restrict__ mask, int* __restrict__ lens) {
  int b = blockIdx.x, l = threadIdx.x;  // 64 blocks x 64 threads
  const int4* row = (const int4*)(mask + (size_t)b * 512);
  int4 v0 = row[l];
  int4 v1 = row[l + 64];
  int s = v0.x + v0.y + v0.z + v0.w + v1.x + v1.y + v1.z + v1.w;
  #pragma unroll
  for (int o = 32; o; o >>= 1) s += __shfl_down(s, o);
  if (l == 0) lens[b] = s;
}

// Compact list of valid chunk-local m-tiles. tl[c*257]=count, entries follow.
// Tile (global) g valid iff (g&3)*128 < lens[g>>2]  (4 tiles of 128 per batch).
__global__ void tiles_k(const int* __restrict__ lens, int* __restrict__ tl,
                        int nchunks) {
  int c = threadIdx.x;
  if (c >= nchunks) return;
  int per = 256 / nchunks;
  int cnt = 0;
  for (int t = 0; t < per; ++t) {
    int g = c * per + t;
    if (((g & 3) * 128) < lens[g >> 2]) tl[c * 257 + 1 + cnt++] = t;
  }
  tl[c * 257] = cnt;
}

// A[m][0:128]=bf16(x[m]), A[m][128:256]=bf16(y[m])
__global__ void build_a(const float* __restrict__ x, const float* __restrict__ y,
                        u16* __restrict__ A) {
  int i4 = blockIdx.x * 256 + threadIdx.x;  // one float4 each; grid 8192
  int e = i4 * 4;
  int m = e >> 8, c = e & 255;
  const float* src = (c < 128) ? (x + (size_t)m * 128 + c)
                               : (y + (size_t)m * 128 + (c - 128));
  float4 v = *(const float4*)src;
  ushort4 o;
  o.x = f2bf(v.x); o.y = f2bf(v.y); o.z = f2bf(v.z); o.w = f2bf(v.w);
  *(ushort4*)&A[e] = o;
}

// out[C][R] bf16 = transpose of in[R][C] f32
__global__ void transpose_k(const float* __restrict__ in, u16* __restrict__ out,
                            int R, int C) {
  __shared__ float tile[32][33];
  int c0 = blockIdx.x * 32, r0 = blockIdx.y * 32;
  int tx = threadIdx.x;
  #pragma unroll
  for (int yy = threadIdx.y; yy < 32; yy += 8)
    tile[yy][tx] = in[(size_t)(r0 + yy) * C + c0 + tx];
  __syncthreads();
  #pragma unroll
  for (int yy = threadIdx.y; yy < 32; yy += 8)
    out[(size_t)(c0 + yy) * R + r0 + tx] = f2bf(tile[tx][yy]);
}

// Sn[m][k] = bf16(S[m][k] / len[m]) for m<64, else 0
__global__ void sn_k(const float* __restrict__ S, const int* __restrict__ lens,
                     u16* __restrict__ Sn) {
  int i4 = blockIdx.x * 256 + threadIdx.x;  // grid 512
  int e = i4 * 4;
  int m = e >> 12;
  float inv = (m < 64) ? (1.0f / (float)lens[m]) : 0.0f;
  float4 v = *(const float4*)(S + e);
  ushort4 o;
  o.x = f2bf(v.x * inv); o.y = f2bf(v.y * inv);
  o.z = f2bf(v.z * inv); o.w = f2bf(v.w * inv);
  *(ushort4*)&Sn[e] = o;
}

// ---------------- main GEMM ----------------
// C[128x128] tile = A[128xK] @ BT[NxK]^T.  BK=64, 4 waves in 2x2, 64x64/wave.
// MODE 0/1: persistent blocks grid-stride over count*32 slots from tile list
//   (slot&31 = n-tile, slot>>5 indexes compacted m-tile list).
// MODE 0: Hout[m][n] = bf16(relu(acc + bias[n]))                  (layer 1)
// MODE 1: Sout[b][n] += sum over valid rows of relu(acc+bias[n])  (layer 2 + pool)
// MODE 2: Fout[m][n] += acc (+bias on y=0), rows<64; split-K over blockIdx.y;
//         each block runs exactly one slot (nslots = gridDim.x).
template <int MODE>
__global__ __launch_bounds__(256, 4) void gemm_k(
    const u16* __restrict__ A, int lda, const u16* __restrict__ BT, int ldb,
    const float* __restrict__ bias, u16* __restrict__ Hout,
    float* __restrict__ Sout, float* __restrict__ Fout,
    const int* __restrict__ lens, const int* __restrict__ tl,
    int K, int Nld, int m_row_base) {
  __shared__ union {
    struct { u16 a[128 * 64]; u16 b[128 * 64]; } st;  // 16KB + 16KB
    u16 outT[128 * 128];                              // MODE0 repack (32KB)
    float colsum[128];                                // MODE1 reduce
  } sm;

  const int tid = threadIdx.x;
  const int wave = tid >> 6;
  const int lane = tid & 63;
  const int wm = wave >> 1, wn = wave & 1;
  const int quad = lane >> 4, l15 = lane & 15;

  const int nslots = (MODE < 2) ? tl[0] * 32 : gridDim.x;

  for (int slot = blockIdx.x; slot < nslots; slot += gridDim.x) {
    int mt, n0, k0, kend;
    int lenb = 1 << 30, bidx = 0;
    if constexpr (MODE < 2) {
      mt = tl[1 + (slot >> 5)];
      n0 = (slot & 31) << 7;
      k0 = 0; kend = K;
      const int gm0 = m_row_base + mt * 128;
      bidx = gm0 >> 9;
      lenb = lens[bidx] - (gm0 & 511);  // rows < lenb are valid (>0 by list)
    } else {
      mt = 0;
      n0 = slot * 128;
      k0 = blockIdx.y * 512;      // split-K x8
      kend = k0 + 512;
    }

    f32x4 acc[4][4];
    #pragma unroll
    for (int i = 0; i < 4; i++)
      #pragma unroll
      for (int j = 0; j < 4; j++) acc[i][j] = (f32x4){0.f, 0.f, 0.f, 0.f};

    // Staging: chunk ci = (wave*4+il)*64+lane; row = ci>>3,
    // kchunk = (ci&7)^(row&7) -> 8 lanes x 16B = 128B contiguous per row.
    const u16* ag[4]; const u16* bg[4];
    #pragma unroll
    for (int il = 0; il < 4; ++il) {
      int ci = (wave * 4 + il) * 64 + lane;
      int m = ci >> 3, c = (ci & 7) ^ (m & 7);
      ag[il] = A + (size_t)(mt * 128 + m) * lda + c * 8;
      bg[il] = BT + (size_t)(n0 + m) * ldb + c * 8;
    }

    for (int kt = k0; kt < kend; kt += 64) {
      #pragma unroll
      for (int il = 0; il < 4; ++il)
        __builtin_amdgcn_global_load_lds(
            (const __attribute__((address_space(1))) void*)(ag[il] + kt),
            (__attribute__((address_space(3))) void*)(&sm.st.a[(wave * 4 + il) * 512]),
            16, 0, 0);
      #pragma unroll
      for (int il = 0; il < 4; ++il)
        __builtin_amdgcn_global_load_lds(
            (const __attribute__((address_space(1))) void*)(bg[il] + kt),
            (__attribute__((address_space(3))) void*)(&sm.st.b[(wave * 4 + il) * 512]),
            16, 0, 0);
      __syncthreads();
      #pragma unroll
      for (int s = 0; s < 2; ++s) {  // two k=32 steps
        s16x8 af[4], bf[4];
        #pragma unroll
        for (int i = 0; i < 4; i++) {
          int m = wm * 64 + i * 16 + l15;
          int c = s * 4 + quad;
          af[i] = *(const s16x8*)&sm.st.a[(m * 8 + (c ^ (m & 7))) * 8];
        }
        #pragma unroll
        for (int j = 0; j < 4; j++) {
          int n = wn * 64 + j * 16 + l15;
          int c = s * 4 + quad;
          bf[j] = *(const s16x8*)&sm.st.b[(n * 8 + (c ^ (n & 7))) * 8];
        }
        #pragma unroll
        for (int i = 0; i < 4; i++)
          #pragma unroll
          for (int j = 0; j < 4; j++)
            acc[i][j] = __builtin_amdgcn_mfma_f32_16x16x32_bf16(af[i], bf[j],
                                                                acc[i][j], 0, 0, 0);
      }
      __syncthreads();
    }

    // epilogues (C/D layout: col = lane&15, row = quad*4 + reg)
    if constexpr (MODE == 0) {
      float bb[4];
      #pragma unroll
      for (int j = 0; j < 4; j++) bb[j] = bias[n0 + wn * 64 + j * 16 + l15];
      #pragma unroll
      for (int i = 0; i < 4; i++)
        #pragma unroll
        for (int j = 0; j < 4; j++) {
          int col = wn * 64 + j * 16 + l15;
          #pragma unroll
          for (int r = 0; r < 4; r++) {
            int row = wm * 64 + i * 16 + quad * 4 + r;
            float v = acc[i][j][r] + bb[j];
            v = v > 0.f ? v : 0.f;
            sm.outT[row * 128 + col] = f2bf(v);
          }
        }
      __syncthreads();
      #pragma unroll
      for (int u = 0; u < 16; ++u) {
        int e = u * 256 + tid;
        int row = e >> 5, c4 = (e & 31) * 4;
        *(uint2*)&Hout[(size_t)(mt * 128 + row) * Nld + n0 + c4] =
            *(const uint2*)&sm.outT[row * 128 + c4];
      }
      __syncthreads();  // protect LDS before next slot's staging
    } else if constexpr (MODE == 1) {
      if (tid < 128) sm.colsum[tid] = 0.f;
      __syncthreads();
      float bb[4];
      #pragma unroll
      for (int j = 0; j < 4; j++) bb[j] = bias[n0 + wn * 64 + j * 16 + l15];
      #pragma unroll
      for (int j = 0; j < 4; j++) {
        float v = 0.f;
        #pragma unroll
        for (int i = 0; i < 4; i++)
          #pragma unroll
          for (int r = 0; r < 4; r++) {
            int row = wm * 64 + i * 16 + quad * 4 + r;
            float t = acc[i][j][r] + bb[j];
            t = t > 0.f ? t : 0.f;
            v += (row < lenb) ? t : 0.f;
          }
        v += __shfl_xor(v, 16);
        v += __shfl_xor(v, 32);
        if (lane < 16) atomicAdd(&sm.colsum[wn * 64 + j * 16 + lane], v);
      }
      __syncthreads();
      if (tid < 128) atomicAdd(&Sout[(size_t)bidx * 4096 + n0 + tid], sm.colsum[tid]);
      __syncthreads();  // protect LDS before next slot's staging
    } else {
      float bb[4];
      #pragma unroll
      for (int j = 0; j < 4; j++)
        bb[j] = (blockIdx.y == 0) ? bias[n0 + wn * 64 + j * 16 + l15] : 0.f;
      #pragma unroll
      for (int i = 0; i < 4; i++)
        #pragma unroll
        for (int j = 0; j < 4; j++) {
          int col = wn * 64 + j * 16 + l15;
          #pragma unroll
          for (int r = 0; r < 4; r++) {
            int row = wm * 64 + i * 16 + quad * 4 + r;
            if (row < 64)
              atomicAdd(&Fout[(size_t)row * Nld + n0 + col], acc[i][j][r] + bb[j]);
          }
        }
    }
  }
}

// ---------------- host ----------------
extern "C" void kernel_launch(void* const* d_in, const int* in_sizes, int n_in,
                              void* d_out, int out_size, void* d_ws, size_t ws_size,
                              hipStream_t stream) {
  const float* x  = (const float*)d_in[0];
  const float* y  = (const float*)d_in[1];
  const int* mask = (const int*)d_in[2];
  const float* W1 = (const float*)d_in[3];
  const float* b1 = (const float*)d_in[4];
  const float* W2 = (const float*)d_in[5];
  const float* b2 = (const float*)d_in[6];
  const float* W3 = (const float*)d_in[7];
  const float* b3 = (const float*)d_in[8];
  float* out = (float*)d_out;

  char* ws = (char*)d_ws;
  size_t off = 0;
  auto alloc = [&](size_t bytes) {
    char* p = ws + off;
    off += (bytes + 255) & ~(size_t)255;
    return p;
  };
  int* lens = (int*)alloc(64 * 4);
  int* tlist = (int*)alloc(4 * 257 * 4);
  float* S  = (float*)alloc((size_t)128 * 4096 * 4);   // padded to 128 rows
  u16* Sn   = (u16*)alloc((size_t)128 * 4096 * 2);
  u16* W1T  = (u16*)alloc((size_t)4096 * 256 * 2);
  u16* W2T  = (u16*)alloc((size_t)4096 * 4096 * 2);
  u16* W3T  = (u16*)alloc((size_t)1024 * 4096 * 2);
  u16* Abuf = (u16*)alloc((size_t)32768 * 256 * 2);
  size_t fixed = off;
  // ws-adaptive H1 chunking: fewer chunks -> more slots/dispatch -> less tail
  size_t h1_full = (size_t)32768 * 4096 * 2;  // 256MB
  int nchunks;
  if (ws_size >= fixed + h1_full) nchunks = 1;
  else if (ws_size >= fixed + h1_full / 2) nchunks = 2;
  else if (ws_size >= fixed + h1_full / 4) nchunks = 4;
  else return;
  const int T = 32768 / nchunks;            // tokens per chunk
  u16* H1 = (u16*)alloc(h1_full / nchunks);

  hipMemsetAsync(S, 0, (size_t)128 * 4096 * 4, stream);
  hipMemsetAsync(out, 0, (size_t)out_size * 4, stream);  // split-K accumulator
  count_k<<<64, 64, 0, stream>>>(mask, lens);
  tiles_k<<<1, 64, 0, stream>>>(lens, tlist, nchunks);
  build_a<<<8192, 256, 0, stream>>>(x, y, Abuf);
  transpose_k<<<dim3(4096 / 32, 256 / 32), dim3(32, 8), 0, stream>>>(W1, W1T, 256, 4096);
  transpose_k<<<dim3(4096 / 32, 4096 / 32), dim3(32, 8), 0, stream>>>(W2, W2T, 4096, 4096);
  transpose_k<<<dim3(1024 / 32, 4096 / 32), dim3(32, 8), 0, stream>>>(W3, W3T, 4096, 1024);

  for (int c = 0; c < nchunks; ++c) {
    gemm_k<0><<<dim3(1024), 256, 0, stream>>>(
        Abuf + (size_t)c * T * 256, 256, W1T, 256, b1, H1, nullptr, nullptr,
        lens, tlist + c * 257, 256, 4096, c * T);
    gemm_k<1><<<dim3(1024), 256, 0, stream>>>(
        H1, 4096, W2T, 4096, b2, nullptr, S, nullptr,
        lens, tlist + c * 257, 4096, 4096, c * T);
  }
  sn_k<<<512, 256, 0, stream>>>(S, lens, Sn);
  gemm_k<2><<<dim3(8, 8), 256, 0, stream>>>(
      Sn, 4096, W3T, 4096, b3, nullptr, nullptr, out, nullptr, nullptr,
      4096, 1024, 0);
}

// Round 7
// 1290.166 us; speedup vs baseline: 1.7663x; 1.2535x over previous
//
#include <hip/hip_runtime.h>

// LinearREncoder: concat(x,y) -> relu(W1)->relu(W2)->(aggregate)->W3 -> masked mean
// B=64 N=512 XD=YD=128 DIN=256 HD=4096 RD=1024, M=B*N=32768 tokens.
// bf16 MFMA (16x16x32) 128x128x64 tiles; layer-3 after masked-sum; persistent
// work-queue blocks (R6). R7: double-buffered LDS K-loop with raw s_barrier +
// partial s_waitcnt vmcnt(8) (AITER pattern): prefetch iter+2 stays in flight
// across the barrier, so the ~500-900cyc staging latency overlaps a full MFMA
// iteration instead of serializing at vmcnt(0) drains (R6: 60% stall, MfmaUtil
// 21.5%). 64KB LDS -> 2 blocks/CU, grid 512.

using u16 = unsigned short;
typedef float f32x4 __attribute__((ext_vector_type(4)));
typedef short s16x8 __attribute__((ext_vector_type(8)));

__device__ __forceinline__ u16 f2bf(float f) {
  union { float f; unsigned u; } v; v.f = f;
  unsigned r = (v.u + 0x7fffu + ((v.u >> 16) & 1u)) >> 16;  // RNE
  return (u16)r;
}

// ---------------- prep kernels ----------------

__global__ void count_k(const int* __restrict__ mask, int* __restrict__ lens) {
  int b = blockIdx.x, l = threadIdx.x;  // 64 blocks x 64 threads
  const int4* row = (const int4*)(mask + (size_t)b * 512);
  int4 v0 = row[l];
  int4 v1 = row[l + 64];
  int s = v0.x + v0.y + v0.z + v0.w + v1.x + v1.y + v1.z + v1.w;
  #pragma unroll
  for (int o = 32; o; o >>= 1) s += __shfl_down(s, o);
  if (l == 0) lens[b] = s;
}

// Compact list of valid chunk-local m-tiles. tl[c*257]=count, entries follow.
__global__ void tiles_k(const int* __restrict__ lens, int* __restrict__ tl,
                        int nchunks) {
  int c = threadIdx.x;
  if (c >= nchunks) return;
  int per = 256 / nchunks;
  int cnt = 0;
  for (int t = 0; t < per; ++t) {
    int g = c * per + t;
    if (((g & 3) * 128) < lens[g >> 2]) tl[c * 257 + 1 + cnt++] = t;
  }
  tl[c * 257] = cnt;
}

// A[m][0:128]=bf16(x[m]), A[m][128:256]=bf16(y[m])
__global__ void build_a(const float* __restrict__ x, const float* __restrict__ y,
                        u16* __restrict__ A) {
  int i4 = blockIdx.x * 256 + threadIdx.x;  // grid 8192
  int e = i4 * 4;
  int m = e >> 8, c = e & 255;
  const float* src = (c < 128) ? (x + (size_t)m * 128 + c)
                               : (y + (size_t)m * 128 + (c - 128));
  float4 v = *(const float4*)src;
  ushort4 o;
  o.x = f2bf(v.x); o.y = f2bf(v.y); o.z = f2bf(v.z); o.w = f2bf(v.w);
  *(ushort4*)&A[e] = o;
}

// out[C][R] bf16 = transpose of in[R][C] f32
__global__ void transpose_k(const float* __restrict__ in, u16* __restrict__ out,
                            int R, int C) {
  __shared__ float tile[32][33];
  int c0 = blockIdx.x * 32, r0 = blockIdx.y * 32;
  int tx = threadIdx.x;
  #pragma unroll
  for (int yy = threadIdx.y; yy < 32; yy += 8)
    tile[yy][tx] = in[(size_t)(r0 + yy) * C + c0 + tx];
  __syncthreads();
  #pragma unroll
  for (int yy = threadIdx.y; yy < 32; yy += 8)
    out[(size_t)(c0 + yy) * R + r0 + tx] = f2bf(tile[tx][yy]);
}

// Sn[m][k] = bf16(S[m][k] / len[m]) for m<64, else 0
__global__ void sn_k(const float* __restrict__ S, const int* __restrict__ lens,
                     u16* __restrict__ Sn) {
  int i4 = blockIdx.x * 256 + threadIdx.x;  // grid 512
  int e = i4 * 4;
  int m = e >> 12;
  float inv = (m < 64) ? (1.0f / (float)lens[m]) : 0.0f;
  float4 v = *(const float4*)(S + e);
  ushort4 o;
  o.x = f2bf(v.x * inv); o.y = f2bf(v.y * inv);
  o.z = f2bf(v.z * inv); o.w = f2bf(v.w * inv);
  *(ushort4*)&Sn[e] = o;
}

// ---------------- main GEMM ----------------
// C[128x128] tile = A[128xK] @ BT[NxK]^T.  BK=64, 4 waves 2x2, 64x64/wave.
// Double-buffered K-loop: iter kt waits vmcnt(8) (drains only its own buffer's
// 8 loads; iter kt+1's 8 stay in flight), raw s_barrier, MFMA, barrier, then
// stages iter kt+2 into the freed buffer. Last iter waits vmcnt(0).
// MODE 0: Hout = bf16(relu(acc+b));  MODE 1: Sout[b][n] += masked colsum;
// MODE 2: Fout += acc (+bias on y=0), rows<64, split-K over blockIdx.y.
template <int MODE>
__global__ __launch_bounds__(256, 2) void gemm_k(
    const u16* __restrict__ A, int lda, const u16* __restrict__ BT, int ldb,
    const float* __restrict__ bias, u16* __restrict__ Hout,
    float* __restrict__ Sout, float* __restrict__ Fout,
    const int* __restrict__ lens, const int* __restrict__ tl,
    int K, int Nld, int m_row_base) {
  __shared__ union {
    struct { u16 a[2][128 * 64]; u16 b[2][128 * 64]; } st;  // 64KB dbuf
    u16 outT[128 * 128];                                    // MODE0 repack 32KB
    float colsum[128];                                      // MODE1 reduce
  } sm;

  const int tid = threadIdx.x;
  const int wave = tid >> 6;
  const int lane = tid & 63;
  const int wm = wave >> 1, wn = wave & 1;
  const int quad = lane >> 4, l15 = lane & 15;

  const int nslots = (MODE < 2) ? tl[0] * 32 : gridDim.x;

  for (int slot = blockIdx.x; slot < nslots; slot += gridDim.x) {
    int mt, n0, k0, kend;
    int lenb = 1 << 30, bidx = 0;
    if constexpr (MODE < 2) {
      mt = tl[1 + (slot >> 5)];
      n0 = (slot & 31) << 7;
      k0 = 0; kend = K;
      const int gm0 = m_row_base + mt * 128;
      bidx = gm0 >> 9;
      lenb = lens[bidx] - (gm0 & 511);  // rows < lenb valid (>0 by list)
    } else {
      mt = 0;
      n0 = slot * 128;
      k0 = blockIdx.y * 512;      // split-K x8
      kend = k0 + 512;
    }

    f32x4 acc[4][4];
    #pragma unroll
    for (int i = 0; i < 4; i++)
      #pragma unroll
      for (int j = 0; j < 4; j++) acc[i][j] = (f32x4){0.f, 0.f, 0.f, 0.f};

    // Staging: chunk ci = (wave*4+il)*64+lane; row = ci>>3,
    // kchunk = (ci&7)^(row&7) -> 8 lanes x 16B = 128B contiguous per row.
    const u16* ag[4]; const u16* bg[4];
    #pragma unroll
    for (int il = 0; il < 4; ++il) {
      int ci = (wave * 4 + il) * 64 + lane;
      int m = ci >> 3, c = (ci & 7) ^ (m & 7);
      ag[il] = A + (size_t)(mt * 128 + m) * lda + c * 8;
      bg[il] = BT + (size_t)(n0 + m) * ldb + c * 8;
    }

    auto stage = [&](int kt, int buf) {
      #pragma unroll
      for (int il = 0; il < 4; ++il)
        __builtin_amdgcn_global_load_lds(
            (const __attribute__((address_space(1))) void*)(ag[il] + kt),
            (__attribute__((address_space(3))) void*)(&sm.st.a[buf][(wave * 4 + il) * 512]),
            16, 0, 0);
      #pragma unroll
      for (int il = 0; il < 4; ++il)
        __builtin_amdgcn_global_load_lds(
            (const __attribute__((address_space(1))) void*)(bg[il] + kt),
            (__attribute__((address_space(3))) void*)(&sm.st.b[buf][(wave * 4 + il) * 512]),
            16, 0, 0);
    };

    stage(k0, 0);                        // prologue: iters 0 and 1 in flight
    if (k0 + 64 < kend) stage(k0 + 64, 1);

    int it = 0;
    for (int kt = k0; kt < kend; kt += 64, ++it) {
      const int cur = it & 1;
      if (kt + 64 < kend)
        __builtin_amdgcn_s_waitcnt(0x0F78);  // vmcnt(8): drain cur's 8 loads
      else
        __builtin_amdgcn_s_waitcnt(0x0F70);  // vmcnt(0): last iter, drain all
      __builtin_amdgcn_s_barrier();          // cur buffer ready for all waves
      #pragma unroll
      for (int s = 0; s < 2; ++s) {  // two k=32 steps
        s16x8 af[4], bf[4];
        #pragma unroll
        for (int i = 0; i < 4; i++) {
          int m = wm * 64 + i * 16 + l15;
          int c = s * 4 + quad;
          af[i] = *(const s16x8*)&sm.st.a[cur][(m * 8 + (c ^ (m & 7))) * 8];
        }
        #pragma unroll
        for (int j = 0; j < 4; j++) {
          int n = wn * 64 + j * 16 + l15;
          int c = s * 4 + quad;
          bf[j] = *(const s16x8*)&sm.st.b[cur][(n * 8 + (c ^ (n & 7))) * 8];
        }
        #pragma unroll
        for (int i = 0; i < 4; i++)
          #pragma unroll
          for (int j = 0; j < 4; j++)
            acc[i][j] = __builtin_amdgcn_mfma_f32_16x16x32_bf16(af[i], bf[j],
                                                                acc[i][j], 0, 0, 0);
      }
      __builtin_amdgcn_s_waitcnt(0x0F70 | 0xF);  // lgkm already 0 via MFMA deps; vm free
      __builtin_amdgcn_s_barrier();          // all waves done reading cur
      if (kt + 128 < kend) stage(kt + 128, cur);
    }
    __syncthreads();  // full drain before LDS reuse in epilogues

    // epilogues (C/D layout: col = lane&15, row = quad*4 + reg)
    if constexpr (MODE == 0) {
      float bb[4];
      #pragma unroll
      for (int j = 0; j < 4; j++) bb[j] = bias[n0 + wn * 64 + j * 16 + l15];
      #pragma unroll
      for (int i = 0; i < 4; i++)
        #pragma unroll
        for (int j = 0; j < 4; j++) {
          int col = wn * 64 + j * 16 + l15;
          #pragma unroll
          for (int r = 0; r < 4; r++) {
            int row = wm * 64 + i * 16 + quad * 4 + r;
            float v = acc[i][j][r] + bb[j];
            v = v > 0.f ? v : 0.f;
            sm.outT[row * 128 + col] = f2bf(v);
          }
        }
      __syncthreads();
      #pragma unroll
      for (int u = 0; u < 16; ++u) {
        int e = u * 256 + tid;
        int row = e >> 5, c4 = (e & 31) * 4;
        *(uint2*)&Hout[(size_t)(mt * 128 + row) * Nld + n0 + c4] =
            *(const uint2*)&sm.outT[row * 128 + c4];
      }
      __syncthreads();  // protect LDS before next slot's staging
    } else if constexpr (MODE == 1) {
      if (tid < 128) sm.colsum[tid] = 0.f;
      __syncthreads();
      float bb[4];
      #pragma unroll
      for (int j = 0; j < 4; j++) bb[j] = bias[n0 + wn * 64 + j * 16 + l15];
      #pragma unroll
      for (int j = 0; j < 4; j++) {
        float v = 0.f;
        #pragma unroll
        for (int i = 0; i < 4; i++)
          #pragma unroll
          for (int r = 0; r < 4; r++) {
            int row = wm * 64 + i * 16 + quad * 4 + r;
            float t = acc[i][j][r] + bb[j];
            t = t > 0.f ? t : 0.f;
            v += (row < lenb) ? t : 0.f;
          }
        v += __shfl_xor(v, 16);
        v += __shfl_xor(v, 32);
        if (lane < 16) atomicAdd(&sm.colsum[wn * 64 + j * 16 + lane], v);
      }
      __syncthreads();
      if (tid < 128) atomicAdd(&Sout[(size_t)bidx * 4096 + n0 + tid], sm.colsum[tid]);
      __syncthreads();  // protect LDS before next slot's staging
    } else {
      float bb[4];
      #pragma unroll
      for (int j = 0; j < 4; j++)
        bb[j] = (blockIdx.y == 0) ? bias[n0 + wn * 64 + j * 16 + l15] : 0.f;
      #pragma unroll
      for (int i = 0; i < 4; i++)
        #pragma unroll
        for (int j = 0; j < 4; j++) {
          int col = wn * 64 + j * 16 + l15;
          #pragma unroll
          for (int r = 0; r < 4; r++) {
            int row = wm * 64 + i * 16 + quad * 4 + r;
            if (row < 64)
              atomicAdd(&Fout[(size_t)row * Nld + n0 + col], acc[i][j][r] + bb[j]);
          }
        }
    }
  }
}

// ---------------- host ----------------
extern "C" void kernel_launch(void* const* d_in, const int* in_sizes, int n_in,
                              void* d_out, int out_size, void* d_ws, size_t ws_size,
                              hipStream_t stream) {
  const float* x  = (const float*)d_in[0];
  const float* y  = (const float*)d_in[1];
  const int* mask = (const int*)d_in[2];
  const float* W1 = (const float*)d_in[3];
  const float* b1 = (const float*)d_in[4];
  const float* W2 = (const float*)d_in[5];
  const float* b2 = (const float*)d_in[6];
  const float* W3 = (const float*)d_in[7];
  const float* b3 = (const float*)d_in[8];
  float* out = (float*)d_out;

  char* ws = (char*)d_ws;
  size_t off = 0;
  auto alloc = [&](size_t bytes) {
    char* p = ws + off;
    off += (bytes + 255) & ~(size_t)255;
    return p;
  };
  int* lens = (int*)alloc(64 * 4);
  int* tlist = (int*)alloc(4 * 257 * 4);
  float* S  = (float*)alloc((size_t)128 * 4096 * 4);   // padded to 128 rows
  u16* Sn   = (u16*)alloc((size_t)128 * 4096 * 2);
  u16* W1T  = (u16*)alloc((size_t)4096 * 256 * 2);
  u16* W2T  = (u16*)alloc((size_t)4096 * 4096 * 2);
  u16* W3T  = (u16*)alloc((size_t)1024 * 4096 * 2);
  u16* Abuf = (u16*)alloc((size_t)32768 * 256 * 2);
  size_t fixed = off;
  size_t h1_full = (size_t)32768 * 4096 * 2;  // 256MB
  int nchunks;
  if (ws_size >= fixed + h1_full) nchunks = 1;
  else if (ws_size >= fixed + h1_full / 2) nchunks = 2;
  else if (ws_size >= fixed + h1_full / 4) nchunks = 4;
  else return;
  const int T = 32768 / nchunks;            // tokens per chunk
  u16* H1 = (u16*)alloc(h1_full / nchunks);

  hipMemsetAsync(S, 0, (size_t)128 * 4096 * 4, stream);
  hipMemsetAsync(out, 0, (size_t)out_size * 4, stream);  // split-K accumulator
  count_k<<<64, 64, 0, stream>>>(mask, lens);
  tiles_k<<<1, 64, 0, stream>>>(lens, tlist, nchunks);
  build_a<<<8192, 256, 0, stream>>>(x, y, Abuf);
  transpose_k<<<dim3(4096 / 32, 256 / 32), dim3(32, 8), 0, stream>>>(W1, W1T, 256, 4096);
  transpose_k<<<dim3(4096 / 32, 4096 / 32), dim3(32, 8), 0, stream>>>(W2, W2T, 4096, 4096);
  transpose_k<<<dim3(1024 / 32, 4096 / 32), dim3(32, 8), 0, stream>>>(W3, W3T, 4096, 1024);

  for (int c = 0; c < nchunks; ++c) {
    gemm_k<0><<<dim3(512), 256, 0, stream>>>(
        Abuf + (size_t)c * T * 256, 256, W1T, 256, b1, H1, nullptr, nullptr,
        lens, tlist + c * 257, 256, 4096, c * T);
    gemm_k<1><<<dim3(512), 256, 0, stream>>>(
        H1, 4096, W2T, 4096, b2, nullptr, S, nullptr,
        lens, tlist + c * 257, 4096, 4096, c * T);
  }
  sn_k<<<512, 256, 0, stream>>>(S, lens, Sn);
  gemm_k<2><<<dim3(8, 8), 256, 0, stream>>>(
      Sn, 4096, W3T, 4096, b3, nullptr, nullptr, out, nullptr, nullptr,
      4096, 1024, 0);
}

// Round 8
// 978.203 us; speedup vs baseline: 2.3296x; 1.3189x over previous
//
#include <hip/hip_runtime.h>

// LinearREncoder: concat(x,y) -> relu(W1)->relu(W2)->(aggregate)->W3 -> masked mean
// B=64 N=512 XD=YD=128 DIN=256 HD=4096 RD=1024. Lengths are PREFIX masks.
// R8: (1) tokens compacted across batches (offs/tok2b) -> no mask logic, 20% less
// GEMM work; pad rows land in dummy batch 64. (2) Weights pre-packed into MFMA
// fragment-tile order -> B loaded straight to registers (coalesced dwordx4,
// reg-dbuf, no LDS, no barrier coupling); LDS holds only the A dbuf (32KB) ->
// 3 blocks/CU. K-loop: raw s_barrier + vmcnt(12) steady-state waits.

using u16 = unsigned short;
typedef float f32x4 __attribute__((ext_vector_type(4)));
typedef short s16x8 __attribute__((ext_vector_type(8)));

__device__ __forceinline__ u16 f2bf(float f) {
  union { float f; unsigned u; } v; v.f = f;
  unsigned r = (v.u + 0x7fffu + ((v.u >> 16) & 1u)) >> 16;  // RNE
  return (u16)r;
}

// ---------------- prep kernels ----------------

// lens[b] = sum of mask ints (bool arrives as int32 0/1)
__global__ void count_k(const int* __restrict__ mask, int* __restrict__ lens) {
  int b = blockIdx.x, l = threadIdx.x;  // 64 x 64
  const int4* row = (const int4*)(mask + (size_t)b * 512);
  int4 v0 = row[l];
  int4 v1 = row[l + 64];
  int s = v0.x + v0.y + v0.z + v0.w + v1.x + v1.y + v1.z + v1.w;
  #pragma unroll
  for (int o = 32; o; o >>= 1) s += __shfl_down(s, o);
  if (l == 0) lens[b] = s;
}

// meta[0..64] = prefix offsets, meta[65] = total, meta[66] = NT = ceil(total/128)
__global__ void meta_k(const int* __restrict__ lens, int* __restrict__ meta) {
  if (threadIdx.x == 0) {
    int acc = 0; meta[0] = 0;
    for (int b = 0; b < 64; ++b) { acc += lens[b]; meta[b + 1] = acc; }
    meta[65] = acc;
    meta[66] = (acc + 127) >> 7;
  }
}

// tok2b[i] = batch of compact token i (binary search), 64 for pad
__global__ void tok2b_k(const int* __restrict__ meta, int* __restrict__ tok2b) {
  int i = blockIdx.x * 256 + threadIdx.x;  // grid 128 -> 32768
  int total = meta[65];
  int b = 64;
  if (i < total) {
    int lo = 0, hi = 64;
    while (hi - lo > 1) { int mid = (lo + hi) >> 1; if (meta[mid] <= i) lo = mid; else hi = mid; }
    b = lo;
  }
  tok2b[i] = b;
}

// Compact A: A[m][0:128]=bf16(x[tok m]), A[m][128:256]=bf16(y[tok m]); pad rows 0
__global__ void build_a(const float* __restrict__ x, const float* __restrict__ y,
                        const int* __restrict__ meta, const int* __restrict__ tok2b,
                        u16* __restrict__ A) {
  int i4 = blockIdx.x * 256 + threadIdx.x;  // grid 8192
  int e = i4 * 4;
  int m = e >> 8, c = e & 255;
  int total = meta[65];
  ushort4 o = {0, 0, 0, 0};
  if (m < total) {
    int b = tok2b[m], t = m - meta[b];
    const float* src = (c < 128) ? x + ((size_t)b * 512 + t) * 128 + c
                                 : y + ((size_t)b * 512 + t) * 128 + (c - 128);
    float4 v = *(const float4*)src;
    o.x = f2bf(v.x); o.y = f2bf(v.y); o.z = f2bf(v.z); o.w = f2bf(v.w);
  }
  *(ushort4*)&A[e] = o;
}

// Pack W[K][N] f32 -> P in MFMA-fragment-tile order, bf16.
// chunk c (16B, 8 elems): lane=c&63; r=c>>6; s=r&1; j=(r>>1)&3; wn=(r>>3)&1;
// ktb=(r>>4)%NKB; nt=(r>>4)/NKB; k=ktb*64+s*32+(lane>>4)*8; n=nt*128+wn*64+j*16+(lane&15)
__global__ void pack_k(const float* __restrict__ W, u16* __restrict__ P,
                       int N, int NKB) {
  long c = (long)blockIdx.x * 256 + threadIdx.x;
  int lane = c & 63; long r = c >> 6;
  int s = r & 1; int j = (r >> 1) & 3; int wn = (r >> 3) & 1;
  long q = r >> 4;
  int ktb = (int)(q % NKB), nt = (int)(q / NKB);
  int k = ktb * 64 + s * 32 + (lane >> 4) * 8;
  int n = nt * 128 + wn * 64 + j * 16 + (lane & 15);
  ushort o[8];
  #pragma unroll
  for (int e = 0; e < 8; ++e) o[e] = f2bf(W[(size_t)(k + e) * N + n]);
  *(uint4*)&P[c * 8] = *(uint4*)o;
}

// Sn[m][k] = bf16(S[m][k] / len[m]) for m<64, else 0
__global__ void sn_k(const float* __restrict__ S, const int* __restrict__ lens,
                     u16* __restrict__ Sn) {
  int i4 = blockIdx.x * 256 + threadIdx.x;  // grid 512
  int e = i4 * 4;
  int m = e >> 12;
  float inv = (m < 64) ? (1.0f / (float)lens[m]) : 0.0f;
  float4 v = *(const float4*)(S + e);
  ushort4 o;
  o.x = f2bf(v.x * inv); o.y = f2bf(v.y * inv);
  o.z = f2bf(v.z * inv); o.w = f2bf(v.w * inv);
  *(ushort4*)&Sn[e] = o;
}

// ---------------- main GEMM ----------------
// C[128x128] = A[128xK] @ B; B pre-packed fragment-tiles, loaded to registers
// (reg-dbuf, 1 iter ahead); A staged to LDS dbuf via global_load_lds.
// K-loop unrolled 2x (K % 128 == 0 for all modes) so reg buffers are static.
// MODE 0: Hout = bf16(relu(acc+b))          (layer 1, compact rows)
// MODE 1: S[batch][n] += relu(acc+b) via per-lane segment-carry (layer 2 + pool)
// MODE 2: Fout += acc (+bias on y=0), rows<64, split-K over blockIdx.y
template <int MODE>
__global__ __launch_bounds__(256, 3) void gemm_k(
    const u16* __restrict__ A, int lda, const u16* __restrict__ BP,
    const float* __restrict__ bias, u16* __restrict__ Hout,
    float* __restrict__ Sout, float* __restrict__ Fout,
    const int* __restrict__ meta, const int* __restrict__ tok2b,
    int K, int Nld, int tile0, int tile_cap) {
  __shared__ union {
    u16 a[2][128 * 64];   // 32KB A dbuf
    u16 outT[128 * 128];  // MODE0 repack (32KB)
  } sm;

  const int tid = threadIdx.x;
  const int wave = tid >> 6;
  const int lane = tid & 63;
  const int wm = wave >> 1, wn = wave & 1;
  const int quad = lane >> 4, l15 = lane & 15;
  const int NKB = K >> 6;

  int nslots;
  if constexpr (MODE < 2) {
    int tc = meta[66] - tile0;
    tc = tc < 0 ? 0 : (tc > tile_cap ? tile_cap : tc);
    nslots = tc * 32;
  } else {
    nslots = gridDim.x;
  }

  for (int slot = blockIdx.x; slot < nslots; slot += gridDim.x) {
    int mt, n0, k0, kend;
    if constexpr (MODE < 2) {
      mt = slot >> 5; n0 = (slot & 31) << 7; k0 = 0; kend = K;
    } else {
      mt = 0; n0 = slot << 7; k0 = blockIdx.y * 512; kend = k0 + 512;
    }

    f32x4 acc[4][4];
    #pragma unroll
    for (int i = 0; i < 4; i++)
      #pragma unroll
      for (int j = 0; j < 4; j++) acc[i][j] = (f32x4){0.f, 0.f, 0.f, 0.f};

    // A staging ptrs: chunk ci=(wave*4+il)*64+lane; row=ci>>3, kc=(ci&7)^(row&7)
    const u16* ag[4];
    #pragma unroll
    for (int il = 0; il < 4; ++il) {
      int ci = (wave * 4 + il) * 64 + lane;
      int m = ci >> 3, c = (ci & 7) ^ (m & 7);
      ag[il] = A + (size_t)(mt * 128 + m) * lda + c * 8;
    }
    // B packed per-wave base
    const u16* bw = BP + (size_t)(n0 >> 7) * NKB * 8192 + wn * 4096 + lane * 8;

    auto stageA = [&](int kt, int buf) {
      #pragma unroll
      for (int il = 0; il < 4; ++il)
        __builtin_amdgcn_global_load_lds(
            (const __attribute__((address_space(1))) void*)(ag[il] + kt),
            (__attribute__((address_space(3))) void*)(&sm.a[buf][(wave * 4 + il) * 512]),
            16, 0, 0);
    };
    auto loadB = [&](int kt, s16x8* dst) {
      const u16* p = bw + (size_t)(kt >> 6) * 8192;
      #pragma unroll
      for (int j = 0; j < 4; j++)
        #pragma unroll
        for (int s = 0; s < 2; s++)
          dst[j * 2 + s] = *(const s16x8*)(p + j * 1024 + s * 512);
    };
    auto compute = [&](int buf, const s16x8* breg) {
      #pragma unroll
      for (int s = 0; s < 2; ++s) {
        s16x8 af[4];
        #pragma unroll
        for (int i = 0; i < 4; i++) {
          int m = wm * 64 + i * 16 + l15;
          int c = (s * 4 + quad) ^ (m & 7);
          af[i] = *(const s16x8*)&sm.a[buf][(m * 8 + c) * 8];
        }
        #pragma unroll
        for (int i = 0; i < 4; i++)
          #pragma unroll
          for (int j = 0; j < 4; j++)
            acc[i][j] = __builtin_amdgcn_mfma_f32_16x16x32_bf16(
                af[i], breg[j * 2 + s], acc[i][j], 0, 0, 0);
      }
    };

    s16x8 breg0[8], breg1[8];
    stageA(k0, 0);
    if (k0 + 64 < kend) stageA(k0 + 64, 1);
    loadB(k0, breg0);

    for (int kt = k0; kt < kend; kt += 128) {  // K % 128 == 0 always
      // sub-iter 0: A buf0 + breg0
      loadB(kt + 64, breg1);
      __builtin_amdgcn_s_waitcnt(0x0F7C);  // vmcnt(12): A(kt),B(kt) retired
      __builtin_amdgcn_s_barrier();
      compute(0, breg0);
      __builtin_amdgcn_s_barrier();
      if (kt + 128 < kend) stageA(kt + 128, 0);
      // sub-iter 1: A buf1 + breg1
      if (kt + 128 < kend) {
        loadB(kt + 128, breg0);
        __builtin_amdgcn_s_waitcnt(0x0F7C);  // vmcnt(12)
      } else {
        __builtin_amdgcn_s_waitcnt(0x0F70);  // vmcnt(0): last iter
      }
      __builtin_amdgcn_s_barrier();
      compute(1, breg1);
      __builtin_amdgcn_s_barrier();
      if (kt + 192 < kend) stageA(kt + 192, 1);
    }
    __syncthreads();

    // epilogues (C/D layout: col = lane&15, row = quad*4 + reg)
    if constexpr (MODE == 0) {
      float bb[4];
      #pragma unroll
      for (int j = 0; j < 4; j++) bb[j] = bias[n0 + wn * 64 + j * 16 + l15];
      #pragma unroll
      for (int i = 0; i < 4; i++)
        #pragma unroll
        for (int j = 0; j < 4; j++) {
          int col = wn * 64 + j * 16 + l15;
          #pragma unroll
          for (int r = 0; r < 4; r++) {
            int row = wm * 64 + i * 16 + quad * 4 + r;
            float v = acc[i][j][r] + bb[j];
            v = v > 0.f ? v : 0.f;
            sm.outT[row * 128 + col] = f2bf(v);
          }
        }
      __syncthreads();
      #pragma unroll
      for (int u = 0; u < 16; ++u) {
        int e = u * 256 + tid;
        int row = e >> 5, c4 = (e & 31) * 4;
        *(uint2*)&Hout[(size_t)(mt * 128 + row) * Nld + n0 + c4] =
            *(const uint2*)&sm.outT[row * 128 + c4];
      }
      __syncthreads();
    } else if constexpr (MODE == 1) {
      float bb[4];
      #pragma unroll
      for (int j = 0; j < 4; j++) bb[j] = bias[n0 + wn * 64 + j * 16 + l15];
      int tb[16];
      const int gbase = tile0 * 128 + mt * 128 + wm * 64 + quad * 4;
      #pragma unroll
      for (int i = 0; i < 4; i++)
        #pragma unroll
        for (int r = 0; r < 4; r++) tb[i * 4 + r] = tok2b[gbase + i * 16 + r];
      #pragma unroll
      for (int j = 0; j < 4; j++) {
        int col = n0 + wn * 64 + j * 16 + l15;
        float sum = 0.f;
        int cb = tb[0];
        #pragma unroll
        for (int idx = 0; idx < 16; ++idx) {
          float t = acc[idx >> 2][j][idx & 3] + bb[j];
          t = t > 0.f ? t : 0.f;
          int b = tb[idx];
          if (b != cb) {
            atomicAdd(&Sout[(size_t)cb * 4096 + col], sum);
            sum = 0.f; cb = b;
          }
          sum += t;
        }
        atomicAdd(&Sout[(size_t)cb * 4096 + col], sum);
      }
    } else {
      float bb[4];
      #pragma unroll
      for (int j = 0; j < 4; j++)
        bb[j] = (blockIdx.y == 0) ? bias[n0 + wn * 64 + j * 16 + l15] : 0.f;
      #pragma unroll
      for (int i = 0; i < 4; i++)
        #pragma unroll
        for (int j = 0; j < 4; j++) {
          int col = wn * 64 + j * 16 + l15;
          #pragma unroll
          for (int r = 0; r < 4; r++) {
            int row = wm * 64 + i * 16 + quad * 4 + r;
            if (row < 64)
              atomicAdd(&Fout[(size_t)row * Nld + n0 + col], acc[i][j][r] + bb[j]);
          }
        }
    }
  }
}

// ---------------- host ----------------
extern "C" void kernel_launch(void* const* d_in, const int* in_sizes, int n_in,
                              void* d_out, int out_size, void* d_ws, size_t ws_size,
                              hipStream_t stream) {
  const float* x  = (const float*)d_in[0];
  const float* y  = (const float*)d_in[1];
  const int* mask = (const int*)d_in[2];
  const float* W1 = (const float*)d_in[3];
  const float* b1 = (const float*)d_in[4];
  const float* W2 = (const float*)d_in[5];
  const float* b2 = (const float*)d_in[6];
  const float* W3 = (const float*)d_in[7];
  const float* b3 = (const float*)d_in[8];
  float* out = (float*)d_out;

  char* ws = (char*)d_ws;
  size_t off = 0;
  auto alloc = [&](size_t bytes) {
    char* p = ws + off;
    off += (bytes + 255) & ~(size_t)255;
    return p;
  };
  int* lens  = (int*)alloc(64 * 4);
  int* meta  = (int*)alloc(70 * 4);
  int* tok2b = (int*)alloc((size_t)32768 * 4);
  float* S   = (float*)alloc((size_t)128 * 4096 * 4);
  u16* Sn    = (u16*)alloc((size_t)128 * 4096 * 2);
  u16* W1P   = (u16*)alloc((size_t)256 * 4096 * 2);
  u16* W2P   = (u16*)alloc((size_t)4096 * 4096 * 2);
  u16* W3P   = (u16*)alloc((size_t)4096 * 1024 * 2);
  u16* Abuf  = (u16*)alloc((size_t)32768 * 256 * 2);
  size_t fixed = off;
  size_t h1_full = (size_t)32768 * 4096 * 2;  // 256MB (256 tiles)
  int nchunks, tile_cap;
  if (ws_size >= fixed + h1_full) { nchunks = 1; tile_cap = 256; }
  else if (ws_size >= fixed + h1_full / 2) { nchunks = 2; tile_cap = 128; }
  else if (ws_size >= fixed + h1_full / 4) { nchunks = 4; tile_cap = 64; }
  else return;
  u16* H1 = (u16*)alloc((size_t)tile_cap * 128 * 4096 * 2);

  hipMemsetAsync(S, 0, (size_t)128 * 4096 * 4, stream);
  hipMemsetAsync(out, 0, (size_t)out_size * 4, stream);
  count_k<<<64, 64, 0, stream>>>(mask, lens);
  meta_k<<<1, 64, 0, stream>>>(lens, meta);
  tok2b_k<<<128, 256, 0, stream>>>(meta, tok2b);
  build_a<<<8192, 256, 0, stream>>>(x, y, meta, tok2b, Abuf);
  pack_k<<<512, 256, 0, stream>>>(W1, W1P, 4096, 4);    // K=256
  pack_k<<<8192, 256, 0, stream>>>(W2, W2P, 4096, 64);  // K=4096
  pack_k<<<2048, 256, 0, stream>>>(W3, W3P, 1024, 64);  // K=4096

  for (int c = 0; c < nchunks; ++c) {
    gemm_k<0><<<dim3(768), 256, 0, stream>>>(
        Abuf + (size_t)c * tile_cap * 128 * 256, 256, W1P, b1, H1, nullptr,
        nullptr, meta, tok2b, 256, 4096, c * tile_cap, tile_cap);
    gemm_k<1><<<dim3(768), 256, 0, stream>>>(
        H1, 4096, W2P, b2, nullptr, S, nullptr,
        meta, tok2b, 4096, 4096, c * tile_cap, tile_cap);
  }
  sn_k<<<512, 256, 0, stream>>>(S, lens, Sn);
  gemm_k<2><<<dim3(8, 8), 256, 0, stream>>>(
      Sn, 4096, W3P, b3, nullptr, nullptr, out,
      meta, tok2b, 4096, 1024, 0, 0);
}

// Round 9
// 820.087 us; speedup vs baseline: 2.7787x; 1.1928x over previous
//
#include <hip/hip_runtime.h>

// LinearREncoder: concat(x,y) -> relu(W1)->relu(W2)->(aggregate)->W3 -> masked mean
// B=64 N=512 XD=YD=128 DIN=256 HD=4096 RD=1024. Lengths are PREFIX masks.
// R8: token compaction + packed-B-to-registers + A-LDS dbuf pipeline (978us,
// MfmaUtil 40%, conflicts 0, FETCH 1.35GB = H1 x8 XCD refetch).
// R9: H1 stored fp8-e4m3 (A-side of layer2 only; weights stay bf16 so the
// mean-surviving weight-quant error is unchanged). MFMA stays bf16: fp8->bf16
// after ds_read_b64 is EXACT (e4m3 values are representable in bf16) via
// v_cvt_pk_f32_fp8 + v_perm high-half pack. Halves A refetch/staging/LDS bytes.

using u16 = unsigned short;
using u8 = unsigned char;
typedef float f32x4 __attribute__((ext_vector_type(4)));
typedef short s16x8 __attribute__((ext_vector_type(8)));
typedef float f32x2 __attribute__((ext_vector_type(2)));

__device__ __forceinline__ u16 f2bf(float f) {
  union { float f; unsigned u; } v; v.f = f;
  unsigned r = (v.u + 0x7fffu + ((v.u >> 16) & 1u)) >> 16;  // RNE
  return (u16)r;
}
__device__ __forceinline__ unsigned fbits(float f) {
  union { float f; unsigned u; } v; v.f = f; return v.u;
}

// ---------------- prep kernels ----------------

// lens[b] = sum of mask ints (bool arrives as int32 0/1)
__global__ void count_k(const int* __restrict__ mask, int* __restrict__ lens) {
  int b = blockIdx.x, l = threadIdx.x;  // 64 x 64
  const int4* row = (const int4*)(mask + (size_t)b * 512);
  int4 v0 = row[l];
  int4 v1 = row[l + 64];
  int s = v0.x + v0.y + v0.z + v0.w + v1.x + v1.y + v1.z + v1.w;
  #pragma unroll
  for (int o = 32; o; o >>= 1) s += __shfl_down(s, o);
  if (l == 0) lens[b] = s;
}

// meta[0..64] = prefix offsets, meta[65] = total, meta[66] = NT = ceil(total/128)
__global__ void meta_k(const int* __restrict__ lens, int* __restrict__ meta) {
  if (threadIdx.x == 0) {
    int acc = 0; meta[0] = 0;
    for (int b = 0; b < 64; ++b) { acc += lens[b]; meta[b + 1] = acc; }
    meta[65] = acc;
    meta[66] = (acc + 127) >> 7;
  }
}

// tok2b[i] = batch of compact token i (binary search), 64 for pad
__global__ void tok2b_k(const int* __restrict__ meta, int* __restrict__ tok2b) {
  int i = blockIdx.x * 256 + threadIdx.x;  // grid 128 -> 32768
  int total = meta[65];
  int b = 64;
  if (i < total) {
    int lo = 0, hi = 64;
    while (hi - lo > 1) { int mid = (lo + hi) >> 1; if (meta[mid] <= i) lo = mid; else hi = mid; }
    b = lo;
  }
  tok2b[i] = b;
}

// Compact A: A[m][0:128]=bf16(x[tok m]), A[m][128:256]=bf16(y[tok m]); pad rows 0
__global__ void build_a(const float* __restrict__ x, const float* __restrict__ y,
                        const int* __restrict__ meta, const int* __restrict__ tok2b,
                        u16* __restrict__ A) {
  int i4 = blockIdx.x * 256 + threadIdx.x;  // grid 8192
  int e = i4 * 4;
  int m = e >> 8, c = e & 255;
  int total = meta[65];
  ushort4 o = {0, 0, 0, 0};
  if (m < total) {
    int b = tok2b[m], t = m - meta[b];
    const float* src = (c < 128) ? x + ((size_t)b * 512 + t) * 128 + c
                                 : y + ((size_t)b * 512 + t) * 128 + (c - 128);
    float4 v = *(const float4*)src;
    o.x = f2bf(v.x); o.y = f2bf(v.y); o.z = f2bf(v.z); o.w = f2bf(v.w);
  }
  *(ushort4*)&A[e] = o;
}

// Pack W[K][N] f32 -> P in MFMA-fragment-tile order, bf16.
__global__ void pack_k(const float* __restrict__ W, u16* __restrict__ P,
                       int N, int NKB) {
  long c = (long)blockIdx.x * 256 + threadIdx.x;
  int lane = c & 63; long r = c >> 6;
  int s = r & 1; int j = (r >> 1) & 3; int wn = (r >> 3) & 1;
  long q = r >> 4;
  int ktb = (int)(q % NKB), nt = (int)(q / NKB);
  int k = ktb * 64 + s * 32 + (lane >> 4) * 8;
  int n = nt * 128 + wn * 64 + j * 16 + (lane & 15);
  ushort o[8];
  #pragma unroll
  for (int e = 0; e < 8; ++e) o[e] = f2bf(W[(size_t)(k + e) * N + n]);
  *(uint4*)&P[c * 8] = *(uint4*)o;
}

// Sn[m][k] = bf16(S[m][k] / len[m]) for m<64, else 0
__global__ void sn_k(const float* __restrict__ S, const int* __restrict__ lens,
                     u16* __restrict__ Sn) {
  int i4 = blockIdx.x * 256 + threadIdx.x;  // grid 512
  int e = i4 * 4;
  int m = e >> 12;
  float inv = (m < 64) ? (1.0f / (float)lens[m]) : 0.0f;
  float4 v = *(const float4*)(S + e);
  ushort4 o;
  o.x = f2bf(v.x * inv); o.y = f2bf(v.y * inv);
  o.z = f2bf(v.z * inv); o.w = f2bf(v.w * inv);
  *(ushort4*)&Sn[e] = o;
}

// ---------------- main GEMM ----------------
// C[128x128] = A[128xK] @ B; B pre-packed fragment-tiles -> registers (dbuf);
// A staged to LDS dbuf via global_load_lds. K-loop unrolled 2x, raw s_barrier
// + vmcnt(12) steady-state (A staging is the manually-guarded part; B regs are
// compiler-guarded).
// MODE 0: A bf16, Hout = fp8(relu(acc+b))    (layer 1, compact rows)
// MODE 1: A fp8 (exact-decode to bf16), S[batch] += relu(acc+b) seg-carry pool
// MODE 2: A bf16, Fout += acc (+bias on y=0), rows<64, split-K over blockIdx.y
template <int MODE>
__global__ __launch_bounds__(256, 3) void gemm_k(
    const void* __restrict__ Av, int lda, const u16* __restrict__ BP,
    const float* __restrict__ bias, u8* __restrict__ Hout,
    float* __restrict__ Sout, float* __restrict__ Fout,
    const int* __restrict__ meta, const int* __restrict__ tok2b,
    int K, int Nld, int tile0, int tile_cap) {
  constexpr bool A8 = (MODE == 1);
  __shared__ union {
    u16 a16[2][128 * 64];   // 32KB A dbuf (bf16 modes)
    u8  a8[2][128 * 64];    // 8KB/buf used (fp8 mode)
    u16 outT[128 * 128];    // (unused in fp8 epilogue)
    u8  outT8[128 * 128];   // MODE0 fp8 repack (16KB)
  } sm;

  const int tid = threadIdx.x;
  const int wave = tid >> 6;
  const int lane = tid & 63;
  const int wm = wave >> 1, wn = wave & 1;
  const int quad = lane >> 4, l15 = lane & 15;
  const int NKB = K >> 6;

  int nslots;
  if constexpr (MODE < 2) {
    int tc = meta[66] - tile0;
    tc = tc < 0 ? 0 : (tc > tile_cap ? tile_cap : tc);
    nslots = tc * 32;
  } else {
    nslots = gridDim.x;
  }

  for (int slot = blockIdx.x; slot < nslots; slot += gridDim.x) {
    int mt, n0, k0, kend;
    if constexpr (MODE < 2) {
      mt = slot >> 5; n0 = (slot & 31) << 7; k0 = 0; kend = K;
    } else {
      mt = 0; n0 = slot << 7; k0 = blockIdx.y * 512; kend = k0 + 512;
    }

    f32x4 acc[4][4];
    #pragma unroll
    for (int i = 0; i < 4; i++)
      #pragma unroll
      for (int j = 0; j < 4; j++) acc[i][j] = (f32x4){0.f, 0.f, 0.f, 0.f};

    // A staging ptrs
    const u8* ag8[2];
    const u16* ag16[4];
    if constexpr (A8) {
      #pragma unroll
      for (int il = 0; il < 2; ++il) {
        int ci = (wave * 2 + il) * 64 + lane;   // 512 chunks x 16B = 8KB
        int m = ci >> 2, c = (ci & 3) ^ (m & 3);
        ag8[il] = (const u8*)Av + (size_t)(mt * 128 + m) * lda + c * 16;
      }
    } else {
      #pragma unroll
      for (int il = 0; il < 4; ++il) {
        int ci = (wave * 4 + il) * 64 + lane;
        int m = ci >> 3, c = (ci & 7) ^ (m & 7);
        ag16[il] = (const u16*)Av + (size_t)(mt * 128 + m) * lda + c * 8;
      }
    }
    const u16* bw = BP + (size_t)(n0 >> 7) * NKB * 8192 + wn * 4096 + lane * 8;

    auto stageA = [&](int kt, int buf) {
      if constexpr (A8) {
        #pragma unroll
        for (int il = 0; il < 2; ++il)
          __builtin_amdgcn_global_load_lds(
              (const __attribute__((address_space(1))) void*)(ag8[il] + kt),
              (__attribute__((address_space(3))) void*)(&sm.a8[buf][(wave * 2 + il) * 1024]),
              16, 0, 0);
      } else {
        #pragma unroll
        for (int il = 0; il < 4; ++il)
          __builtin_amdgcn_global_load_lds(
              (const __attribute__((address_space(1))) void*)(ag16[il] + kt),
              (__attribute__((address_space(3))) void*)(&sm.a16[buf][(wave * 4 + il) * 512]),
              16, 0, 0);
      }
    };
    auto loadB = [&](int kt, s16x8* dst) {
      const u16* p = bw + (size_t)(kt >> 6) * 8192;
      #pragma unroll
      for (int j = 0; j < 4; j++)
        #pragma unroll
        for (int s = 0; s < 2; s++)
          dst[j * 2 + s] = *(const s16x8*)(p + j * 1024 + s * 512);
    };
    auto compute = [&](int buf, const s16x8* breg) {
      #pragma unroll
      for (int s = 0; s < 2; ++s) {
        s16x8 af[4];
        #pragma unroll
        for (int i = 0; i < 4; i++) {
          int m = wm * 64 + i * 16 + l15;
          if constexpr (A8) {
            int kc = s * 2 + (quad >> 1);
            int addr = (m * 4 + (kc ^ (m & 3))) * 16 + (quad & 1) * 8;
            int2 d = *(const int2*)&sm.a8[buf][addr];
            f32x2 f0 = __builtin_amdgcn_cvt_pk_f32_fp8(d.x, 0);
            f32x2 f1 = __builtin_amdgcn_cvt_pk_f32_fp8(d.x, 1);
            f32x2 f2 = __builtin_amdgcn_cvt_pk_f32_fp8(d.y, 0);
            f32x2 f3 = __builtin_amdgcn_cvt_pk_f32_fp8(d.y, 1);
            int4 u;  // bf16 = high half of f32 (exact for e4m3 values)
            u.x = __builtin_amdgcn_perm(fbits(f0.y), fbits(f0.x), 0x07060302);
            u.y = __builtin_amdgcn_perm(fbits(f1.y), fbits(f1.x), 0x07060302);
            u.z = __builtin_amdgcn_perm(fbits(f2.y), fbits(f2.x), 0x07060302);
            u.w = __builtin_amdgcn_perm(fbits(f3.y), fbits(f3.x), 0x07060302);
            af[i] = *(const s16x8*)&u;
          } else {
            int c = (s * 4 + quad) ^ (m & 7);
            af[i] = *(const s16x8*)&sm.a16[buf][(m * 8 + c) * 8];
          }
        }
        #pragma unroll
        for (int i = 0; i < 4; i++)
          #pragma unroll
          for (int j = 0; j < 4; j++)
            acc[i][j] = __builtin_amdgcn_mfma_f32_16x16x32_bf16(
                af[i], breg[j * 2 + s], acc[i][j], 0, 0, 0);
      }
    };

    s16x8 breg0[8], breg1[8];
    stageA(k0, 0);
    if (k0 + 64 < kend) stageA(k0 + 64, 1);
    loadB(k0, breg0);

    for (int kt = k0; kt < kend; kt += 128) {  // K % 128 == 0 always
      loadB(kt + 64, breg1);
      __builtin_amdgcn_s_waitcnt(0x0F7C);  // vmcnt(12): A(cur) certainly drained
      __builtin_amdgcn_s_barrier();
      compute(0, breg0);
      __builtin_amdgcn_s_barrier();
      if (kt + 128 < kend) stageA(kt + 128, 0);
      if (kt + 128 < kend) {
        loadB(kt + 128, breg0);
        __builtin_amdgcn_s_waitcnt(0x0F7C);  // vmcnt(12)
      } else {
        __builtin_amdgcn_s_waitcnt(0x0F70);  // vmcnt(0): last iter
      }
      __builtin_amdgcn_s_barrier();
      compute(1, breg1);
      __builtin_amdgcn_s_barrier();
      if (kt + 192 < kend) stageA(kt + 192, 1);
    }
    __syncthreads();

    // epilogues (C/D layout: col = lane&15, row = quad*4 + reg)
    if constexpr (MODE == 0) {
      float bb[4];
      #pragma unroll
      for (int j = 0; j < 4; j++) bb[j] = bias[n0 + wn * 64 + j * 16 + l15];
      #pragma unroll
      for (int i = 0; i < 4; i++)
        #pragma unroll
        for (int j = 0; j < 4; j++) {
          int col = wn * 64 + j * 16 + l15;
          #pragma unroll
          for (int r = 0; r < 4; r++) {
            int row = wm * 64 + i * 16 + quad * 4 + r;
            float v = acc[i][j][r] + bb[j];
            v = v > 0.f ? v : 0.f;
            sm.outT8[row * 128 + col] =
                (u8)(__builtin_amdgcn_cvt_pk_fp8_f32(v, v, 0, false) & 0xff);
          }
        }
      __syncthreads();
      #pragma unroll
      for (int u = 0; u < 4; ++u) {
        int e = u * 256 + tid;
        int row = e >> 3, c16 = (e & 7) * 16;
        *(uint4*)&Hout[(size_t)(mt * 128 + row) * Nld + n0 + c16] =
            *(const uint4*)&sm.outT8[row * 128 + c16];
      }
      __syncthreads();
    } else if constexpr (MODE == 1) {
      float bb[4];
      #pragma unroll
      for (int j = 0; j < 4; j++) bb[j] = bias[n0 + wn * 64 + j * 16 + l15];
      int tb[16];
      const int gbase = tile0 * 128 + mt * 128 + wm * 64 + quad * 4;
      #pragma unroll
      for (int i = 0; i < 4; i++)
        #pragma unroll
        for (int r = 0; r < 4; r++) tb[i * 4 + r] = tok2b[gbase + i * 16 + r];
      #pragma unroll
      for (int j = 0; j < 4; j++) {
        int col = n0 + wn * 64 + j * 16 + l15;
        float sum = 0.f;
        int cb = tb[0];
        #pragma unroll
        for (int idx = 0; idx < 16; ++idx) {
          float t = acc[idx >> 2][j][idx & 3] + bb[j];
          t = t > 0.f ? t : 0.f;
          int b = tb[idx];
          if (b != cb) {
            atomicAdd(&Sout[(size_t)cb * 4096 + col], sum);
            sum = 0.f; cb = b;
          }
          sum += t;
        }
        atomicAdd(&Sout[(size_t)cb * 4096 + col], sum);
      }
    } else {
      float bb[4];
      #pragma unroll
      for (int j = 0; j < 4; j++)
        bb[j] = (blockIdx.y == 0) ? bias[n0 + wn * 64 + j * 16 + l15] : 0.f;
      #pragma unroll
      for (int i = 0; i < 4; i++)
        #pragma unroll
        for (int j = 0; j < 4; j++) {
          int col = wn * 64 + j * 16 + l15;
          #pragma unroll
          for (int r = 0; r < 4; r++) {
            int row = wm * 64 + i * 16 + quad * 4 + r;
            if (row < 64)
              atomicAdd(&Fout[(size_t)row * Nld + n0 + col], acc[i][j][r] + bb[j]);
          }
        }
    }
  }
}

// ---------------- host ----------------
extern "C" void kernel_launch(void* const* d_in, const int* in_sizes, int n_in,
                              void* d_out, int out_size, void* d_ws, size_t ws_size,
                              hipStream_t stream) {
  const float* x  = (const float*)d_in[0];
  const float* y  = (const float*)d_in[1];
  const int* mask = (const int*)d_in[2];
  const float* W1 = (const float*)d_in[3];
  const float* b1 = (const float*)d_in[4];
  const float* W2 = (const float*)d_in[5];
  const float* b2 = (const float*)d_in[6];
  const float* W3 = (const float*)d_in[7];
  const float* b3 = (const float*)d_in[8];
  float* out = (float*)d_out;

  char* ws = (char*)d_ws;
  size_t off = 0;
  auto alloc = [&](size_t bytes) {
    char* p = ws + off;
    off += (bytes + 255) & ~(size_t)255;
    return p;
  };
  int* lens  = (int*)alloc(64 * 4);
  int* meta  = (int*)alloc(70 * 4);
  int* tok2b = (int*)alloc((size_t)32768 * 4);
  float* S   = (float*)alloc((size_t)128 * 4096 * 4);
  u16* Sn    = (u16*)alloc((size_t)128 * 4096 * 2);
  u16* W1P   = (u16*)alloc((size_t)256 * 4096 * 2);
  u16* W2P   = (u16*)alloc((size_t)4096 * 4096 * 2);
  u16* W3P   = (u16*)alloc((size_t)4096 * 1024 * 2);
  u16* Abuf  = (u16*)alloc((size_t)32768 * 256 * 2);
  size_t fixed = off;
  size_t h1_full = (size_t)32768 * 4096;  // 134MB fp8 (256 tiles)
  int nchunks, tile_cap;
  if (ws_size >= fixed + h1_full) { nchunks = 1; tile_cap = 256; }
  else if (ws_size >= fixed + h1_full / 2) { nchunks = 2; tile_cap = 128; }
  else if (ws_size >= fixed + h1_full / 4) { nchunks = 4; tile_cap = 64; }
  else return;
  u8* H1 = (u8*)alloc(h1_full / nchunks);

  hipMemsetAsync(S, 0, (size_t)128 * 4096 * 4, stream);
  hipMemsetAsync(out, 0, (size_t)out_size * 4, stream);
  count_k<<<64, 64, 0, stream>>>(mask, lens);
  meta_k<<<1, 64, 0, stream>>>(lens, meta);
  tok2b_k<<<128, 256, 0, stream>>>(meta, tok2b);
  build_a<<<8192, 256, 0, stream>>>(x, y, meta, tok2b, Abuf);
  pack_k<<<512, 256, 0, stream>>>(W1, W1P, 4096, 4);    // K=256
  pack_k<<<8192, 256, 0, stream>>>(W2, W2P, 4096, 64);  // K=4096
  pack_k<<<2048, 256, 0, stream>>>(W3, W3P, 1024, 64);  // K=4096

  for (int c = 0; c < nchunks; ++c) {
    gemm_k<0><<<dim3(768), 256, 0, stream>>>(
        Abuf + (size_t)c * tile_cap * 128 * 256, 256, W1P, b1, H1,
        nullptr, nullptr, meta, tok2b, 256, 4096, c * tile_cap, tile_cap);
    gemm_k<1><<<dim3(768), 256, 0, stream>>>(
        H1, 4096, W2P, b2, nullptr, S, nullptr,
        meta, tok2b, 4096, 4096, c * tile_cap, tile_cap);
  }
  sn_k<<<512, 256, 0, stream>>>(S, lens, Sn);
  gemm_k<2><<<dim3(8, 8), 256, 0, stream>>>(
      Sn, 4096, W3P, b3, nullptr, nullptr, out,
      meta, tok2b, 4096, 1024, 0, 0);
}